// Round 7
// baseline (459.938 us; speedup 1.0000x reference)
//
#include <hip/hip_runtime.h>
#include <hip/hip_bf16.h>

// Problem dims
constexpr int N_TOK = 2048;   // T*B
constexpr int C_    = 256;    // in features (== R == OUT)
constexpr int NE    = 64;     // experts
constexpr int D_    = 65536;  // R*OUT centroid dim
constexpr float DECAYF = 0.999f;
constexpr float OMD    = 0.001f;
constexpr float ALPHA  = OMD / 2048.0f;   // (1-decay)/N
constexpr float RTHRESH = 1e-5f;
constexpr int CHMAX = 8448;
constexpr int SA_GRIDX = 512;

using bf16x8 = __attribute__((ext_vector_type(8))) short;
using f32x4  = __attribute__((ext_vector_type(4))) float;
using u16 = unsigned short;

// ---------- workspace layout (float offsets) ----------
constexpr size_t OFF_S     = 0;        // 65536  S = X^T X (full)
constexpr size_t OFF_XSUM  = 65536;    // 256
constexpr size_t OFF_G     = 65792;    // 65536  G = W^T W (full)
constexpr size_t OFF_M     = 131328;   // 16384  M = cen @ W
constexpr size_t OFF_WB    = 147712;   // 256    Wb = b^T W
constexpr size_t OFF_BB    = 147968;   // 16     bb[0] = ||b||^2
constexpr size_t OFF_SUMR  = 147984;   // 64     sum_n resp
constexpr size_t OFF_A     = 148048;   // 16384  A = resp^T X
constexpr size_t OFF_CC0   = 164432;   // 4096   cen cen^T
constexpr size_t OFF_RR    = 168528;   // 4096   resp^T resp
constexpr size_t OFF_CNT   = 172624;   // 64     per-expert token counts (uint)
constexpr size_t OFF_CN2   = 172688;   // 64     (unused; cn2 == diag(CC0))
constexpr size_t OFF_CB    = 172752;   // 64
constexpr size_t OFF_TSLOT = 172816;   // 2048   per-token writer count (int)
constexpr size_t ZFLOATS   = 174864;
// overwritten-before-read zone:
constexpr size_t OFF_RESP  = 174864;   // 131072
constexpr size_t OFF_AG    = 174864;   // 16384 (overlay after resp dead)
constexpr size_t OFF_MA    = 191248;   // 4096
constexpr size_t OFF_AGA   = 195344;   // 4096
constexpr size_t OFF_AWB   = 199440;   // 64
constexpr size_t OFF_CHE   = 199504;   // 8448
constexpr size_t OFF_CHB   = 207952;   // 8448
constexpr size_t OFF_NCH   = 216400;   // 16
constexpr size_t OFF_Y     = 305936;   // 524288 y = X @ pw^T
constexpr size_t OFF_CNEW  = 830224;   // 4194304 ; ALSO reused (before k_cnew), sequentially:
                                       //   k_G3 partials (10*64*4096 = 2.62M floats)
                                       //   then k_M3 partials (128*16384 = 2.10M) or k_M (256*16384 = 4.19M)
                                       //   then k_CCp partials (512*4096 = 2.10M)
constexpr size_t OFF_TIDX  = 5024528;  // 131072 (int)
constexpr size_t OFF_TOKR  = 5155600;  // 131072
// ---- bf16 extension. SIZE AUDIT (R2/R4 lesson -- the overlap bug):
//   bf16[256][65536] = 16,777,216 u16 = 8,388,608 floats
//   bf16[ 64][65536] =  4,194,304 u16 = 2,097,152 floats
constexpr size_t OFF_WTH   = 5286672;               // + 8,388,608
constexpr size_t OFF_WTL   = 13675280;              // + 8,388,608
constexpr size_t OFF_CENH  = 22063888;              // + 2,097,152
constexpr size_t OFF_CENL  = 24161040;              // + 2,097,152
constexpr size_t WS_FAST_END = 13675280;            // 54.7 MB (wth only)
constexpr size_t WS_FULL_END = 26258192;            // 105.0 MB (R6 fill counter: ws = 256 MiB)

__device__ __forceinline__ unsigned pack_bf2(float a, float b) {
  __hip_bfloat16 ha = __float2bfloat16(a), hb = __float2bfloat16(b);
  unsigned short ua = *reinterpret_cast<unsigned short*>(&ha);
  unsigned short ub = *reinterpret_cast<unsigned short*>(&hb);
  return (unsigned)ua | ((unsigned)ub << 16);
}

__device__ __forceinline__ void split_bf(float x, u16& h, u16& lo) {
  __hip_bfloat16 hb = __float2bfloat16(x);
  float hf = __bfloat162float(hb);
  __hip_bfloat16 lb = __float2bfloat16(x - hf);   // residual exact in fp32
  h  = *reinterpret_cast<unsigned short*>(&hb);
  lo = *reinterpret_cast<unsigned short*>(&lb);
}

// ---------------- bb[0] = ||b||^2 ----------------
__global__ __launch_bounds__(256) void k_bb(const float* __restrict__ bmap, float* __restrict__ bb) {
  int base = blockIdx.x * 16384 + threadIdx.x;
  float s = 0.f;
  for (int q = 0; q < 64; q++) { float v = bmap[base + q * 256]; s = fmaf(v, v, s); }
  __shared__ float red[256];
  red[threadIdx.x] = s;
  __syncthreads();
  for (int k = 128; k > 0; k >>= 1) {
    if (threadIdx.x < k) red[threadIdx.x] += red[threadIdx.x + k];
    __syncthreads();
  }
  if (threadIdx.x == 0) atomicAdd(&bb[0], red[0]);
}

// ======== generic 64x64 gram-style tile (S / A2 / RR2) ========
template<int KCHUNK>
__device__ __forceinline__ void gemm_tt_tile(
    const float* __restrict__ Aop, int lda, int ca,
    const float* __restrict__ Bop, int ldb, int cb,
    int d0, float* __restrict__ Out, int ldo, int ro, int co) {
  __shared__ float Wa[32][68], Wb[32][68];
  int t = threadIdx.x;
  int tx = t & 15, ty = t >> 4;
  int lr = t >> 3, lc = (t & 7) * 8;
  float acc[4][4] = {};
  for (int dk = 0; dk < KCHUNK; dk += 32) {
    const float* Arow = &Aop[(size_t)(d0 + dk + lr) * lda + ca];
    const float* Brow = &Bop[(size_t)(d0 + dk + lr) * ldb + cb];
    float4 a0 = *(const float4*)&Arow[lc];
    float4 a1 = *(const float4*)&Arow[lc + 4];
    float4 b0 = *(const float4*)&Brow[lc];
    float4 b1 = *(const float4*)&Brow[lc + 4];
    __syncthreads();
    *(float4*)&Wa[lr][lc]     = a0;
    *(float4*)&Wa[lr][lc + 4] = a1;
    *(float4*)&Wb[lr][lc]     = b0;
    *(float4*)&Wb[lr][lc + 4] = b1;
    __syncthreads();
    #pragma unroll
    for (int k = 0; k < 32; k++) {
      float4 ra4 = *(const float4*)&Wa[k][ty * 4];
      float4 rb4 = *(const float4*)&Wb[k][tx * 4];
      float ra[4] = {ra4.x, ra4.y, ra4.z, ra4.w};
      float rb[4] = {rb4.x, rb4.y, rb4.z, rb4.w};
      #pragma unroll
      for (int i = 0; i < 4; i++)
        #pragma unroll
        for (int j = 0; j < 4; j++)
          acc[i][j] = fmaf(ra[i], rb[j], acc[i][j]);
    }
  }
  #pragma unroll
  for (int i = 0; i < 4; i++)
    #pragma unroll
    for (int j = 0; j < 4; j++)
      atomicAdd(&Out[(size_t)(ro + ty * 4 + i) * ldo + co + tx * 4 + j], acc[i][j]);
}

// ==================== bf16 conversion pass ====================

// ---- k_Tw: W (65536x256 fp32) -> Wt bf16 [256][65536] (transposed); hi always,
// lo (residual) only when wlo!=0 (full path).
__global__ __launch_bounds__(256) void k_Tw(const float* __restrict__ W,
    u16* __restrict__ wth, u16* __restrict__ wtl, int wlo) {
  __shared__ float Ls[32][257];
  int t = threadIdx.x;
  int d0 = blockIdx.x * 32;
  int r = t >> 3, c8 = (t & 7) * 32;
  #pragma unroll
  for (int q = 0; q < 8; q++) {
    float4 v = *(const float4*)&W[(size_t)(d0 + r) * 256 + c8 + q * 4];
    Ls[r][c8 + q * 4 + 0] = v.x; Ls[r][c8 + q * 4 + 1] = v.y;
    Ls[r][c8 + q * 4 + 2] = v.z; Ls[r][c8 + q * 4 + 3] = v.w;
  }
  __syncthreads();
  int dq = (t & 3) * 8;
  #pragma unroll
  for (int pQ = 0; pQ < 4; pQ++) {
    int c = pQ * 64 + (t >> 2);
    unsigned hw[4], lw[4];
    #pragma unroll
    for (int q = 0; q < 4; q++) {
      u16 h0, l0, h1, l1;
      split_bf(Ls[dq + 2 * q][c], h0, l0);
      split_bf(Ls[dq + 2 * q + 1][c], h1, l1);
      hw[q] = (unsigned)h0 | ((unsigned)h1 << 16);
      lw[q] = (unsigned)l0 | ((unsigned)l1 << 16);
    }
    size_t o = (size_t)c * 65536 + d0 + dq;
    *(uint4*)&wth[o] = make_uint4(hw[0], hw[1], hw[2], hw[3]);
    if (wlo) *(uint4*)&wtl[o] = make_uint4(lw[0], lw[1], lw[2], lw[3]);
  }
}

// ---- k_Tc: cen (64x65536 fp32) -> cen_hi/cen_lo bf16 (row-major split)
__global__ __launch_bounds__(256) void k_Tc(const float* __restrict__ cen,
    u16* __restrict__ ch, u16* __restrict__ cl) {
  size_t base = ((size_t)blockIdx.x * 256 + threadIdx.x) * 8;
  float4 a = *(const float4*)&cen[base];
  float4 b = *(const float4*)&cen[base + 4];
  float v[8] = {a.x, a.y, a.z, a.w, b.x, b.y, b.z, b.w};
  unsigned hw[4], lw[4];
  #pragma unroll
  for (int q = 0; q < 4; q++) {
    u16 h0, l0, h1, l1;
    split_bf(v[2 * q], h0, l0);
    split_bf(v[2 * q + 1], h1, l1);
    hw[q] = (unsigned)h0 | ((unsigned)h1 << 16);
    lw[q] = (unsigned)l0 | ((unsigned)l1 << 16);
  }
  *(uint4*)&ch[base] = make_uint4(hw[0], hw[1], hw[2], hw[3]);
  *(uint4*)&cl[base] = make_uint4(lw[0], lw[1], lw[2], lw[3]);
}

// ==================== k_G3: G = Wt_hi Wt_hi^T via MFMA (R5/R6-proven) ========
__global__ __launch_bounds__(256) void k_G3(const u16* __restrict__ wth,
    float* __restrict__ part) {
  int kb = blockIdx.x;
  int p = blockIdx.y;
  int ti = 0, rem0 = p;
  while (rem0 >= 4 - ti) { rem0 -= 4 - ti; ti++; }
  int tj = ti + rem0;
  bool two = (ti != tj);
  const u16* srcA = wth + (size_t)(ti * 64) * 65536;
  const u16* srcB = wth + (size_t)(tj * 64) * 65536;
  __shared__ __align__(16) u16 Ta[8 * 68 * 8], Tb[8 * 68 * 8];
  int t = threadIdx.x, l = t & 63, w = t >> 6;
  int m0 = w * 16, lm = l & 15, g = l >> 4;
  int scol = t >> 3, skseg = t & 7;
  f32x4 acc[4] = {};
  for (int cc = 0; cc < 16; cc++) {
    int k0 = kb * 1024 + cc * 64;
    __syncthreads();   // protect previous chunk's frag reads
    {
      uint4 a0 = *(const uint4*)(srcA + (size_t)scol * 65536 + k0 + skseg * 8);
      uint4 a1 = *(const uint4*)(srcA + (size_t)(scol + 32) * 65536 + k0 + skseg * 8);
      *(uint4*)(Ta + (skseg * 68 + scol) * 8) = a0;
      *(uint4*)(Ta + (skseg * 68 + scol + 32) * 8) = a1;
      if (two) {
        uint4 b0 = *(const uint4*)(srcB + (size_t)scol * 65536 + k0 + skseg * 8);
        uint4 b1 = *(const uint4*)(srcB + (size_t)(scol + 32) * 65536 + k0 + skseg * 8);
        *(uint4*)(Tb + (skseg * 68 + scol) * 8) = b0;
        *(uint4*)(Tb + (skseg * 68 + scol + 32) * 8) = b1;
      }
    }
    __syncthreads();
    const u16* TBp = two ? Tb : Ta;
    #pragma unroll
    for (int ks = 0; ks < 2; ks++) {
      int kq = ks * 4 + g;
      bf16x8 av = *(const bf16x8*)(Ta + (kq * 68 + m0 + lm) * 8);
      #pragma unroll
      for (int j = 0; j < 4; j++) {
        bf16x8 bv = *(const bf16x8*)(TBp + (kq * 68 + j * 16 + lm) * 8);
        acc[j] = __builtin_amdgcn_mfma_f32_16x16x32_bf16(av, bv, acc[j], 0, 0, 0);
      }
    }
  }
  // C/D layout: col = lane&15, row = (lane>>4)*4 + reg  [m89-verified]
  float* pp = &part[((size_t)p * 64 + kb) * 4096];
  #pragma unroll
  for (int j = 0; j < 4; j++)
    #pragma unroll
    for (int r = 0; r < 4; r++)
      pp[(m0 + (l >> 4) * 4 + r) * 64 + j * 16 + lm] = acc[j][r];
}

// ---- reduce 64 k-partials -> G (mirror off-diagonal pairs) ----
__global__ __launch_bounds__(256) void k_Gred(const float* __restrict__ part,
    float* __restrict__ G) {
  int p = blockIdx.y;
  int ti = 0, rem0 = p;
  while (rem0 >= 4 - ti) { rem0 -= 4 - ti; ti++; }
  int tj = ti + rem0;
  int i = blockIdx.x * 256 + threadIdx.x;   // 0..4095
  const float* base = part + (size_t)p * 64 * 4096 + i;
  float s = 0.f;
  for (int kb = 0; kb < 64; kb++) s += base[(size_t)kb * 4096];
  int r = i >> 6, c = i & 63;
  G[(ti * 64 + r) * C_ + tj * 64 + c] = s;
  if (ti != tj) G[(tj * 64 + c) * C_ + ti * 64 + r] = s;
}

// ---- fallback G (R1-proven: fused convert, partials) --
__global__ __launch_bounds__(256) void k_Gslow(const float* __restrict__ W,
    float* __restrict__ part) {
  int p = blockIdx.y;
  int ti = 0, rem0 = p;
  while (rem0 >= 4 - ti) { rem0 -= 4 - ti; ti++; }
  int tj = ti + rem0;
  int c1 = ti * 64, c2 = tj * 64;
  int d0 = blockIdx.x * 1024;
  __shared__ unsigned short Wat[64][40], Wbt[64][40];
  int t = threadIdx.x;
  int h = t >> 7;
  int rem = t & 127;
  int k2 = rem >> 3;
  int c4b = rem & 7;
  int cbase = h ? c2 : c1;
  unsigned short (*dst)[40] = h ? Wbt : Wat;
  int l = t & 63, w = t >> 6;
  int m0 = w * 16;
  int lm = l & 15, q8 = (l >> 4) * 8;
  f32x4 acc[4] = {};
  for (int dk = 0; dk < 1024; dk += 32) {
    __syncthreads();
    #pragma unroll
    for (int it = 0; it < 2; it++) {
      int c4 = c4b + it * 8;
      const float* rp = &W[(size_t)(d0 + dk + k2 * 2) * C_ + cbase + c4 * 4];
      float4 g0 = *(const float4*)rp;
      float4 g1 = *(const float4*)(rp + C_);
      *(unsigned*)&dst[c4 * 4 + 0][k2 * 2] = pack_bf2(g0.x, g1.x);
      *(unsigned*)&dst[c4 * 4 + 1][k2 * 2] = pack_bf2(g0.y, g1.y);
      *(unsigned*)&dst[c4 * 4 + 2][k2 * 2] = pack_bf2(g0.z, g1.z);
      *(unsigned*)&dst[c4 * 4 + 3][k2 * 2] = pack_bf2(g0.w, g1.w);
    }
    __syncthreads();
    bf16x8 av = *(const bf16x8*)&Wat[m0 + lm][q8];
    #pragma unroll
    for (int j = 0; j < 4; j++) {
      bf16x8 bv = *(const bf16x8*)&Wbt[j * 16 + lm][q8];
      acc[j] = __builtin_amdgcn_mfma_f32_16x16x32_bf16(av, bv, acc[j], 0, 0, 0);
    }
  }
  float* pp = &part[((size_t)p * 64 + blockIdx.x) * 4096];
  #pragma unroll
  for (int j = 0; j < 4; j++)
    #pragma unroll
    for (int r = 0; r < 4; r++)
      pp[(m0 + (l >> 4) * 4 + r) * 64 + j * 16 + lm] = acc[j][r];
}

// ==== k_M3: M = cen @ W via split-bf16 MFMA (hh + hl + lh; ll dropped).
// Error ~2^-17 rel over K=65536 -> logit err ~4e-5 (fp32-class; threshold 0.8,
// current margin 0.125). Structure = clone of proven k_G3 staging.
// grid (128 kb, 4 cb), K-chunk 512, partials -> k_Mred. ====
__global__ __launch_bounds__(256) void k_M3(const u16* __restrict__ cenh,
    const u16* __restrict__ cenl, const u16* __restrict__ wth,
    const u16* __restrict__ wtl, float* __restrict__ mpart) {
  int kb = blockIdx.x;
  int c0 = blockIdx.y * 64;
  const u16* srcBH = wth + (size_t)c0 * 65536;
  const u16* srcBL = wtl + (size_t)c0 * 65536;
  __shared__ __align__(16) u16 TAH[8 * 68 * 8], TAL[8 * 68 * 8];
  __shared__ __align__(16) u16 TBH[8 * 68 * 8], TBL[8 * 68 * 8];
  int t = threadIdx.x, l = t & 63;
  int m0 = (t >> 6) * 16, lm = l & 15, g = l >> 4;
  int scol = t >> 3, skseg = t & 7;
  f32x4 acc[4] = {};
  for (int cc = 0; cc < 8; cc++) {
    int k0 = kb * 512 + cc * 64;
    __syncthreads();   // protect previous chunk's frag reads
    {
      size_t o0 = (size_t)scol * 65536 + k0 + skseg * 8;
      size_t o1 = (size_t)(scol + 32) * 65536 + k0 + skseg * 8;
      uint4 ah0 = *(const uint4*)(cenh + o0), ah1 = *(const uint4*)(cenh + o1);
      uint4 al0 = *(const uint4*)(cenl + o0), al1 = *(const uint4*)(cenl + o1);
      uint4 bh0 = *(const uint4*)(srcBH + o0), bh1 = *(const uint4*)(srcBH + o1);
      uint4 bl0 = *(const uint4*)(srcBL + o0), bl1 = *(const uint4*)(srcBL + o1);
      int s0 = (skseg * 68 + scol) * 8, s1 = (skseg * 68 + scol + 32) * 8;
      *(uint4*)(TAH + s0) = ah0; *(uint4*)(TAH + s1) = ah1;
      *(uint4*)(TAL + s0) = al0; *(uint4*)(TAL + s1) = al1;
      *(uint4*)(TBH + s0) = bh0; *(uint4*)(TBH + s1) = bh1;
      *(uint4*)(TBL + s0) = bl0; *(uint4*)(TBL + s1) = bl1;
    }
    __syncthreads();
    #pragma unroll
    for (int ks = 0; ks < 2; ks++) {
      int kq = ks * 4 + g;
      bf16x8 ah = *(const bf16x8*)(TAH + (kq * 68 + m0 + lm) * 8);
      bf16x8 al = *(const bf16x8*)(TAL + (kq * 68 + m0 + lm) * 8);
      #pragma unroll
      for (int j = 0; j < 4; j++) {
        bf16x8 bh = *(const bf16x8*)(TBH + (kq * 68 + j * 16 + lm) * 8);
        bf16x8 bl = *(const bf16x8*)(TBL + (kq * 68 + j * 16 + lm) * 8);
        acc[j] = __builtin_amdgcn_mfma_f32_16x16x32_bf16(ah, bh, acc[j], 0, 0, 0);
        acc[j] = __builtin_amdgcn_mfma_f32_16x16x32_bf16(ah, bl, acc[j], 0, 0, 0);
        acc[j] = __builtin_amdgcn_mfma_f32_16x16x32_bf16(al, bh, acc[j], 0, 0, 0);
      }
    }
  }
  float* pp = &mpart[(size_t)kb * 16384];
  #pragma unroll
  for (int j = 0; j < 4; j++)
    #pragma unroll
    for (int r = 0; r < 4; r++)
      pp[(m0 + (l >> 4) * 4 + r) * 256 + c0 + j * 16 + lm] = acc[j][r];
}

// ==================== shared pipeline ====================

// ---- S = X^T X ----
__global__ __launch_bounds__(256) void k_S(const float* __restrict__ x, float* __restrict__ S) {
  int p = blockIdx.y;
  int ti = p >> 2, tj = p & 3;
  gemm_tt_tile<256>(x, C_, ti * 64, x, C_, tj * 64, blockIdx.x * 256,
                    S, C_, ti * 64, tj * 64);
}

// ---- A = resp^T X ----
__global__ __launch_bounds__(256) void k_A2(const float* __restrict__ resp,
    const float* __restrict__ x, float* __restrict__ A) {
  gemm_tt_tile<256>(resp, NE, 0, x, C_, blockIdx.y * 64, blockIdx.x * 256,
                    A, C_, 0, blockIdx.y * 64);
}

// ---- RR = resp^T resp ----
__global__ __launch_bounds__(256) void k_RR2(const float* __restrict__ resp,
    float* __restrict__ RR) {
  gemm_tt_tile<256>(resp, NE, 0, resp, NE, 0, blockIdx.x * 256, RR, NE, 0, 0);
}

// ---- sumresp ----
__global__ __launch_bounds__(256) void k_sr(const float* __restrict__ resp,
    float* __restrict__ sumresp) {
  int e = threadIdx.x & 63, part = threadIdx.x >> 6;
  int n0 = blockIdx.x * 256 + part * 64;
  float s = 0.f;
  for (int n = n0; n < n0 + 64; n++) s += resp[n * NE + e];
  __shared__ float red[256];
  red[threadIdx.x] = s;
  __syncthreads();
  if (part == 0)
    atomicAdd(&sumresp[e], red[e] + red[64 + e] + red[128 + e] + red[192 + e]);
}

// ---------------- Xsum ----------------
__global__ __launch_bounds__(256) void k_xsum(const float* __restrict__ x, float* __restrict__ xsum) {
  int n0 = blockIdx.x * 64;
  int c = threadIdx.x;
  float s = 0.f;
  for (int n = 0; n < 64; n++) s += x[(n0 + n) * C_ + c];
  atomicAdd(&xsum[c], s);
}

// ---- M = cen @ W fp32 (fallback; R3/R5-proven). ksplit 256x256 ----
__global__ __launch_bounds__(256) void k_M(const float* __restrict__ cen,
    const float* __restrict__ W, float* __restrict__ mpart) {
  int kb = blockIdx.x;
  int c0 = blockIdx.y * 64;
  int d0 = kb * 256;
  __shared__ float As[32][68];
  __shared__ float Bs[32][68];
  int t = threadIdx.x;
  int tx = t & 15, ty = t >> 4;
  int e = t >> 2, dg = t & 3;
  int lr = t >> 3, lc = (t & 7) * 8;
  float acc[4][4] = {};
  for (int dk = 0; dk < 256; dk += 32) {
    const float* cr = &cen[(size_t)e * D_ + d0 + dk];
    float4 cv0 = *(const float4*)&cr[dg * 4];
    float4 cv1 = *(const float4*)&cr[16 + dg * 4];
    const float* wr = &W[(size_t)(d0 + dk + lr) * C_ + c0];
    float4 w0 = *(const float4*)&wr[lc];
    float4 w1 = *(const float4*)&wr[lc + 4];
    __syncthreads();
    As[dg * 4 + 0][e] = cv0.x; As[dg * 4 + 1][e] = cv0.y;
    As[dg * 4 + 2][e] = cv0.z; As[dg * 4 + 3][e] = cv0.w;
    As[16 + dg * 4 + 0][e] = cv1.x; As[16 + dg * 4 + 1][e] = cv1.y;
    As[16 + dg * 4 + 2][e] = cv1.z; As[16 + dg * 4 + 3][e] = cv1.w;
    *(float4*)&Bs[lr][lc]     = w0;
    *(float4*)&Bs[lr][lc + 4] = w1;
    __syncthreads();
    #pragma unroll 8
    for (int k = 0; k < 32; k++) {
      float4 ra4 = *(const float4*)&As[k][ty * 4];
      float4 rb4 = *(const float4*)&Bs[k][tx * 4];
      float ra[4] = {ra4.x, ra4.y, ra4.z, ra4.w};
      float rb[4] = {rb4.x, rb4.y, rb4.z, rb4.w};
      #pragma unroll
      for (int i = 0; i < 4; i++)
        #pragma unroll
        for (int j = 0; j < 4; j++)
          acc[i][j] = fmaf(ra[i], rb[j], acc[i][j]);
    }
  }
  float* pp = &mpart[(size_t)kb * 16384];
  #pragma unroll
  for (int i = 0; i < 4; i++)
    *(float4*)&pp[(ty * 4 + i) * C_ + c0 + tx * 4] = *(float4*)&acc[i][0];
}

// ---- reduce k-partials -> M. grid (64, nkb/64); atomicAdd into zeroed M ----
__global__ __launch_bounds__(256) void k_Mred(const float* __restrict__ mpart,
    float* __restrict__ M) {
  int i = blockIdx.x * 256 + threadIdx.x;
  int kb0 = blockIdx.y * 64;
  float s = 0.f;
  #pragma unroll 8
  for (int kb = 0; kb < 64; kb++) s += mpart[(size_t)(kb0 + kb) * 16384 + i];
  atomicAdd(&M[i], s);
}

// ---- CC partials + cb: 512 blocks x 128-d chunk ----
__global__ __launch_bounds__(256) void k_CCp(const float* __restrict__ cen,
    const float* __restrict__ bmap, float* __restrict__ part,
    float* __restrict__ cb) {
  int d0 = blockIdx.x * 128;
  __shared__ float cs[32][68];
  __shared__ float red[256];
  int t = threadIdx.x;
  int e = t >> 2, dg = t & 3;
  int tx = t & 15, ty = t >> 4;
  float acc[4][4] = {};
  float cbp = 0.f;
  for (int dk = 0; dk < 128; dk += 32) {
    const float* cr = &cen[(size_t)e * D_ + d0 + dk];
    float4 v0 = *(const float4*)&cr[dg * 4];
    float4 v1 = *(const float4*)&cr[16 + dg * 4];
    const float* br = &bmap[d0 + dk];
    float4 b0 = *(const float4*)&br[dg * 4];
    float4 b1 = *(const float4*)&br[16 + dg * 4];
    cbp += v0.x * b0.x + v0.y * b0.y + v0.z * b0.z + v0.w * b0.w
         + v1.x * b1.x + v1.y * b1.y + v1.z * b1.z + v1.w * b1.w;
    __syncthreads();
    cs[dg * 4 + 0][e] = v0.x; cs[dg * 4 + 1][e] = v0.y;
    cs[dg * 4 + 2][e] = v0.z; cs[dg * 4 + 3][e] = v0.w;
    cs[16 + dg * 4 + 0][e] = v1.x; cs[16 + dg * 4 + 1][e] = v1.y;
    cs[16 + dg * 4 + 2][e] = v1.z; cs[16 + dg * 4 + 3][e] = v1.w;
    __syncthreads();
    #pragma unroll
    for (int k = 0; k < 32; k++) {
      float4 ra4 = *(const float4*)&cs[k][ty * 4];
      float4 rb4 = *(const float4*)&cs[k][tx * 4];
      float ra[4] = {ra4.x, ra4.y, ra4.z, ra4.w};
      float rb[4] = {rb4.x, rb4.y, rb4.z, rb4.w};
      #pragma unroll
      for (int i = 0; i < 4; i++)
        #pragma unroll
        for (int j = 0; j < 4; j++)
          acc[i][j] = fmaf(ra[i], rb[j], acc[i][j]);
    }
  }
  float* pp = &part[(size_t)blockIdx.x * 4096];
  #pragma unroll
  for (int i = 0; i < 4; i++)
    *(float4*)&pp[(ty * 4 + i) * 64 + tx * 4] = *(float4*)&acc[i][0];
  red[t] = cbp;
  __syncthreads();
  if (t < 64)
    atomicAdd(&cb[t], red[t * 4] + red[t * 4 + 1] + red[t * 4 + 2] + red[t * 4 + 3]);
}

// ---- reduce 512 CC partials -> CC0 (diag serves as cn2) ----
__global__ __launch_bounds__(256) void k_CCred(const float* __restrict__ part,
    float* __restrict__ CC0) {
  int i = (blockIdx.x & 15) * 256 + threadIdx.x;
  int kb0 = (blockIdx.x >> 4) * 64;
  float s = 0.f;
  #pragma unroll 8
  for (int kb = 0; kb < 64; kb++) s += part[(size_t)(kb0 + kb) * 4096 + i];
  atomicAdd(&CC0[i], s);
}

// ---------------- Wb[c] = sum_d b[d] W[d,c] (skip all-zero b chunks) ----------
__global__ __launch_bounds__(256) void k_Wb(const float* __restrict__ bmap,
    const float* __restrict__ W, float* __restrict__ Wb) {
  int d0 = blockIdx.x * 256;
  int c = threadIdx.x;
  __shared__ float bs[256];
  __shared__ int any;
  if (c == 0) any = 0;
  __syncthreads();
  float bv = bmap[d0 + c];
  bs[c] = bv;
  if (bv != 0.f) any = 1;
  __syncthreads();
  if (any == 0) return;
  float s = 0.f;
  for (int d = 0; d < 256; d++) s = fmaf(bs[d], W[(size_t)(d0 + d) * C_ + c], s);
  atomicAdd(&Wb[c], s);
}

// ---------------- y = X @ pw^T ----------------
__global__ __launch_bounds__(256) void k_y(const float* __restrict__ x,
    const float* __restrict__ pw, float* __restrict__ y) {
  int n0 = blockIdx.x * 64, k0 = blockIdx.y * 64;
  __shared__ float Xs[64][17], Ps[64][17];
  int t = threadIdx.x;
  int tx = t & 15, ty = t >> 4;
  int r = t >> 2, q4 = (t & 3) * 4;
  float acc[4][4] = {};
  for (int j0 = 0; j0 < 256; j0 += 16) {
    float4 va = *(const float4*)&x[(n0 + r) * C_ + j0 + q4];
    float4 vb = *(const float4*)&pw[(k0 + r) * C_ + j0 + q4];
    __syncthreads();
    Xs[r][q4] = va.x; Xs[r][q4+1] = va.y; Xs[r][q4+2] = va.z; Xs[r][q4+3] = va.w;
    Ps[r][q4] = vb.x; Ps[r][q4+1] = vb.y; Ps[r][q4+2] = vb.z; Ps[r][q4+3] = vb.w;
    __syncthreads();
    #pragma unroll
    for (int k = 0; k < 16; k++) {
      float ra[4], rb[4];
      #pragma unroll
      for (int i = 0; i < 4; i++) ra[i] = Xs[ty*4 + i][k];
      #pragma unroll
      for (int j = 0; j < 4; j++) rb[j] = Ps[tx*4 + j][k];
      #pragma unroll
      for (int i = 0; i < 4; i++)
        #pragma unroll
        for (int j = 0; j < 4; j++)
          acc[i][j] = fmaf(ra[i], rb[j], acc[i][j]);
    }
  }
  #pragma unroll
  for (int i = 0; i < 4; i++)
    #pragma unroll
    for (int j = 0; j < 4; j++)
      y[(n0 + ty*4 + i) * C_ + k0 + tx*4 + j] = acc[i][j];
}

// ------- resp softmax (cn2 read from diag of CC0) --------
__global__ __launch_bounds__(64) void k_resp(const float* __restrict__ x,
    const float* __restrict__ u, const float* __restrict__ M,
    const float* __restrict__ CC0, const float* __restrict__ cb,
    float* __restrict__ resp) {
  int n = blockIdx.x;
  int e = threadIdx.x;
  __shared__ float xs[256];
  *(float4*)&xs[e * 4] = *(const float4*)&x[n * C_ + e * 4];
  __syncthreads();
  const float* Me = M + e * C_;
  float s = 0.f;
  #pragma unroll 8
  for (int j = 0; j < 256; j += 4) {
    float4 m4 = *(const float4*)&Me[j];
    s = fmaf(xs[j],   m4.x, s);
    s = fmaf(xs[j+1], m4.y, s);
    s = fmaf(xs[j+2], m4.z, s);
    s = fmaf(xs[j+3], m4.w, s);
  }
  float uu = u[n * NE + e];
  float g = -logf(-logf(uu));
  float logit = 2.0f * (s + cb[e]) - CC0[e * 65] + g;   // TAU == 1
  float m = logit;
  for (int off = 32; off > 0; off >>= 1) m = fmaxf(m, __shfl_xor(m, off));
  float ex = expf(logit - m);
  float sum = ex;
  for (int off = 32; off > 0; off >>= 1) sum += __shfl_xor(sum, off);
  resp[n * NE + e] = ex / sum;
}

// ------- routing (NO cap — r3 lesson) -------
__global__ __launch_bounds__(256) void k_route(const float* __restrict__ resp,
    unsigned int* __restrict__ cnt, int* __restrict__ tokidx,
    float* __restrict__ tokr, int* __restrict__ tslot) {
  int n = blockIdx.x * 256 + threadIdx.x;
  int s = 0;
  #pragma unroll 4
  for (int e = 0; e < NE; e++) {
    float r = resp[n * NE + e];
    if (r > RTHRESH) {
      unsigned pos = atomicAdd(&cnt[e], 1u);
      tokidx[e * 2048 + pos] = n;
      tokr[e * 2048 + pos] = r;
      s++;
    }
  }
  tslot[n] = s;
}

// ------- planner (parallelized: old 1-thread loop was up to ~8448 serial
// dependent stores ~ 10-30us latency-bound; now scan + 256-wide fill) -------
__global__ __launch_bounds__(256) void k_plan(const unsigned int* __restrict__ cnt,
    int* __restrict__ che, int* __restrict__ chb, int* __restrict__ nch) {
  __shared__ int cbase[65];
  __shared__ int ncs[64];
  int t = threadIdx.x;
  if (t < 64) ncs[t] = ((int)cnt[t] + 15) >> 4;
  __syncthreads();
  if (t == 0) {
    int s = 0;
    for (int e = 0; e < 64; e++) { cbase[e] = s; s += ncs[e]; }
    cbase[64] = s;
    nch[0] = s < CHMAX ? s : CHMAX;
  }
  __syncthreads();
  for (int e = 0; e < 64; e++) {
    int b0 = cbase[e], nc = cbase[e + 1] - b0;
    for (int i = t; i < nc; i += 256) {
      int idx = b0 + i;
      if (idx < CHMAX) { che[idx] = e; chb[idx] = i * 16; }
    }
  }
}

// ---------------- AG = A @ G, AWb ----------------
__global__ __launch_bounds__(256) void k_ag(const float* __restrict__ A,
    const float* __restrict__ G, const float* __restrict__ Wb,
    float* __restrict__ AG, float* __restrict__ AWb) {
  int e = blockIdx.x, c = threadIdx.x;
  float s = 0.f;
  for (int cp = 0; cp < C_; cp++) s = fmaf(A[e * C_ + cp], G[cp * C_ + c], s);
  AG[e * C_ + c] = s;
  float p = A[e * C_ + c] * Wb[c];
  __shared__ float red[256];
  red[c] = p;
  __syncthreads();
  for (int k = 128; k > 0; k >>= 1) {
    if (c < k) red[c] += red[c + k];
    __syncthreads();
  }
  if (c == 0) AWb[e] = red[0];
}

// ---------------- MA = M A^T, AGA = AG A^T ----------------
__global__ __launch_bounds__(256) void k_small64(const float* __restrict__ M,
    const float* __restrict__ A, const float* __restrict__ AG,
    float* __restrict__ MA, float* __restrict__ AGA) {
  int e = blockIdx.x;
  int f = threadIdx.x >> 2, q = threadIdx.x & 3;
  float s1 = 0.f, s2 = 0.f;
  for (int c = q * 64; c < q * 64 + 64; c++) {
    float a = A[f * C_ + c];
    s1 = fmaf(M[e * C_ + c], a, s1);
    s2 = fmaf(AG[e * C_ + c], a, s2);
  }
  __shared__ float r1[256], r2[256];
  r1[threadIdx.x] = s1; r2[threadIdx.x] = s2;
  __syncthreads();
  if (q == 0) {
    MA[e * NE + f]  = r1[f*4] + r1[f*4+1] + r1[f*4+2] + r1[f*4+3];
    AGA[e * NE + f] = r2[f*4] + r2[f*4+1] + r2[f*4+2] + r2[f*4+3];
  }
}

// ------- cnew[e,d] = decay*cen + alpha*(A_e.W_d + sr_e*b_d)  [MFMA, R6-proven]
__global__ __launch_bounds__(256) void k_cnew(const float* __restrict__ A,
    const float* __restrict__ sumresp, const float* __restrict__ cen,
    const float* __restrict__ bmap, const float* __restrict__ W,
    float* __restrict__ cnew) {
  int d0 = blockIdx.x * 64;
  __shared__ __align__(16) u16 Abf[64 * 264];
  __shared__ __align__(16) u16 Wt[64 * 264];
  __shared__ float srs[64];
  int t = threadIdx.x, l = t & 63;
  int m0 = (t >> 6) * 16, lm = l & 15, g = l >> 4;
  {
    int e = t >> 2, c0 = (t & 3) * 64;
    const float* ar = &A[e * C_ + c0];
    u16* dst = &Abf[e * 264 + c0];
    #pragma unroll
    for (int q = 0; q < 8; q++) {
      float4 v0 = *(const float4*)&ar[q * 8];
      float4 v1 = *(const float4*)&ar[q * 8 + 4];
      *(uint4*)&dst[q * 8] = make_uint4(pack_bf2(v0.x, v0.y), pack_bf2(v0.z, v0.w),
                                        pack_bf2(v1.x, v1.y), pack_bf2(v1.z, v1.w));
    }
    int r = t >> 2;
    const float* wr = &W[(size_t)(d0 + r) * C_ + c0];
    u16* wdst = &Wt[r * 264 + c0];
    #pragma unroll
    for (int q = 0; q < 8; q++) {
      float4 v0 = *(const float4*)&wr[q * 8];
      float4 v1 = *(const float4*)&wr[q * 8 + 4];
      *(uint4*)&wdst[q * 8] = make_uint4(pack_bf2(v0.x, v0.y), pack_bf2(v0.z, v0.w),
                                         pack_bf2(v1.x, v1.y), pack_bf2(v1.z, v1.w));
    }
    if (t < 64) srs[t] = sumresp[t];
  }
  __syncthreads();
  f32x4 acc[4] = {};
  #pragma unroll
  for (int kk = 0; kk < 8; kk++) {
    bf16x8 av = *(const bf16x8*)&Abf[(m0 + lm) * 264 + kk * 32 + g * 8];
    #pragma unroll
    for (int j = 0; j < 4; j++) {
      bf16x8 bv = *(const bf16x8*)&Wt[(j * 16 + lm) * 264 + kk * 32 + g * 8];
      acc[j] = __builtin_amdgcn_mfma_f32_16x16x32_bf16(av, bv, acc[j], 0, 0, 0);
    }
  }
  #pragma unroll
  for (int j = 0; j < 4; j++) {
    int d = d0 + j * 16 + lm;
    float bv = bmap[d];
    #pragma unroll
    for (int r = 0; r < 4; r++) {
      int e = m0 + g * 4 + r;
      size_t o = (size_t)e * D_ + d;
      cnew[o] = DECAYF * cen[o] + ALPHA * (acc[j][r] + srs[e] * bv);
    }
  }
}

// ---------------- out init with bias ----------------
__global__ __launch_bounds__(256) void k_bias(const float* __restrict__ pwB, float* __restrict__ out) {
  int idx = blockIdx.x * 256 + threadIdx.x;
  out[idx] = pwB[idx & 255];
}

// ------- stage A: dense grouped GEMM -------
__global__ __launch_bounds__(256) void k_sA(const int* __restrict__ che,
    const int* __restrict__ chb, const int* __restrict__ nch,
    const unsigned int* __restrict__ cnt, const int* __restrict__ tokidx,
    const float* __restrict__ tokr, const int* __restrict__ tslot,
    const float* __restrict__ y, const float* __restrict__ cnew,
    float* __restrict__ out) {
  int nchv = nch[0];
  int i0 = blockIdx.y * 128;
  __shared__ int nsh[16]; __shared__ float rsh[16]; __shared__ int wsh[16];
  __shared__ float Ys[16][260];
  __shared__ float Bs[32][132];
  int t = threadIdx.x;
  for (int ch = blockIdx.x; ch < nchv; ch += SA_GRIDX) {
    int e = che[ch], base = chb[ch];
    int c = (int)cnt[e];
    __syncthreads();
    if (t < 16) {
      int idx = base + t;
      if (idx < c) {
        int n = tokidx[e * 2048 + idx];
        nsh[t] = n; rsh[t] = tokr[e * 2048 + idx]; wsh[t] = tslot[n];
      } else { nsh[t] = 0; rsh[t] = 0.f; wsh[t] = 2; }
    }
    __syncthreads();
    {
      int row = t >> 4, c0 = (t & 15) * 16;
      const float* yr = &y[nsh[row] * C_ + c0];
      float4 v0 = *(const float4*)&yr[0];
      float4 v1 = *(const float4*)&yr[4];
      float4 v2 = *(const float4*)&yr[8];
      float4 v3 = *(const float4*)&yr[12];
      *(float4*)&Ys[row][c0]      = v0;
      *(float4*)&Ys[row][c0 + 4]  = v1;
      *(float4*)&Ys[row][c0 + 8]  = v2;
      *(float4*)&Ys[row][c0 + 12] = v3;
    }
    int tx = t & 31, ty = t >> 5;
    int br = t >> 1, bk = (t & 1) * 16;
    float acc[2][4] = {};
    for (int k0 = 0; k0 < 256; k0 += 32) {
      const float* Brow = &cnew[(size_t)e * D_ + (size_t)(i0 + br) * C_ + k0 + bk];
      float4 b0 = *(const float4*)&Brow[0];
      float4 b1 = *(const float4*)&Brow[4];
      float4 b2 = *(const float4*)&Brow[8];
      float4 b3 = *(const float4*)&Brow[12];
      __syncthreads();
      Bs[bk+0][br]  = b0.x; Bs[bk+1][br]  = b0.y; Bs[bk+2][br]  = b0.z; Bs[bk+3][br]  = b0.w;
      Bs[bk+4][br]  = b1.x; Bs[bk+5][br]  = b1.y; Bs[bk+6][br]  = b1.z; Bs[bk+7][br]  = b1.w;
      Bs[bk+8][br]  = b2.x; Bs[bk+9][br]  = b2.y; Bs[bk+10][br] = b2.z; Bs[bk+11][br] = b2.w;
      Bs[bk+12][br] = b3.x; Bs[bk+13][br] = b3.y; Bs[bk+14][br] = b3.z; Bs[bk+15][br] = b3.w;
      __syncthreads();
      #pragma unroll
      for (int kk = 0; kk < 32; kk++) {
        float a0 = Ys[ty*2 + 0][k0 + kk];
        float a1 = Ys[ty*2 + 1][k0 + kk];
        float4 bv = *(const float4*)&Bs[kk][tx*4];
        acc[0][0] = fmaf(a0, bv.x, acc[0][0]); acc[0][1] = fmaf(a0, bv.y, acc[0][1]);
        acc[0][2] = fmaf(a0, bv.z, acc[0][2]); acc[0][3] = fmaf(a0, bv.w, acc[0][3]);
        acc[1][0] = fmaf(a1, bv.x, acc[1][0]); acc[1][1] = fmaf(a1, bv.y, acc[1][1]);
        acc[1][2] = fmaf(a1, bv.z, acc[1][2]); acc[1][3] = fmaf(a1, bv.w, acc[1][3]);
      }
    }
    #pragma unroll
    for (int i = 0; i < 2; i++) {
      int tk = ty*2 + i;
      float r = rsh[tk];
      if (r == 0.f) continue;
      int n = nsh[tk];
      float* op = &out[n * C_ + i0 + tx*4];
      if (wsh[tk] == 1) {
        float4 cur = *(const float4*)op;
        cur.x += r * acc[i][0]; cur.y += r * acc[i][1];
        cur.z += r * acc[i][2]; cur.w += r * acc[i][3];
        *(float4*)op = cur;
      } else {
        atomicAdd(op + 0, r * acc[i][0]);
        atomicAdd(op + 1, r * acc[i][1]);
        atomicAdd(op + 2, r * acc[i][2]);
        atomicAdd(op + 3, r * acc[i][3]);
      }
    }
  }
}

// ---- gsum = sum G .* S ----
__global__ __launch_bounds__(256) void k_gs(const float* __restrict__ G,
    const float* __restrict__ S, float* __restrict__ gsum) {
  int base = blockIdx.x * 1024 + threadIdx.x;
  float s = 0.f;
  #pragma unroll
  for (int q = 0; q < 4; q++) {
    int i = base + q * 256;
    s = fmaf(G[i], S[i], s);
  }
  __shared__ float red[256];
  red[threadIdx.x] = s;
  __syncthreads();
  for (int k = 128; k > 0; k >>= 1) {
    if (threadIdx.x < k) red[threadIdx.x] += red[threadIdx.x + k];
    __syncthreads();
  }
  if (threadIdx.x == 0) atomicAdd(gsum, red[0]);
}

// ---------------- loss assembly ----------------
__global__ __launch_bounds__(256) void k_finalize(
    const float* __restrict__ gsum, const float* __restrict__ M,
    const float* __restrict__ A, const float* __restrict__ AG,
    const float* __restrict__ CC0, const float* __restrict__ RR,
    const float* __restrict__ MA, const float* __restrict__ AGA,
    const float* __restrict__ Xsum, const float* __restrict__ Wb,
    const float* __restrict__ bb, const float* __restrict__ sr,
    const float* __restrict__ cb, const float* __restrict__ AWb,
    float* __restrict__ out) {
  int t = threadIdx.x;
  float a_gs = (t == 0) ? gsum[0] : 0.f;
  float a_am = 0.f, a_aag = 0.f;
  for (int i = t; i < 16384; i += 256) {
    float a = A[i];
    a_am  = fmaf(M[i], a, a_am);
    a_aag = fmaf(AG[i], a, a_aag);
  }
  float a_cc = 0.f, a_ma = 0.f, a_aga = 0.f, a_cbsr = 0.f, a_awbsr = 0.f, a_srsr = 0.f;
  for (int p = t; p < 4096; p += 256) {
    float r = RR[p];
    int e = p >> 6, f = p & 63;
    float srf = sr[f];
    a_cc    = fmaf(r, CC0[p], a_cc);
    a_ma    = fmaf(r, MA[p], a_ma);
    a_aga   = fmaf(r, AGA[p], a_aga);
    a_cbsr  = fmaf(r * cb[e], srf, a_cbsr);
    a_awbsr = fmaf(r * AWb[e], srf, a_awbsr);
    a_srsr  = fmaf(r * sr[e], srf, a_srsr);
  }
  float a_xw = Xsum[t] * Wb[t];
  float a_srcb = 0.f, a_srawb = 0.f, a_sr2 = 0.f;
  if (t < 64) { float s = sr[t]; a_srcb = s * cb[t]; a_srawb = s * AWb[t]; a_sr2 = s * s; }
  float v[13] = {a_gs, a_am, a_aag, a_cc, a_ma, a_aga, a_cbsr, a_awbsr, a_srsr,
                 a_xw, a_srcb, a_srawb, a_sr2};
  __shared__ float red[256];
  __shared__ float tot[13];
  for (int q = 0; q < 13; q++) {
    red[t] = v[q];
    __syncthreads();
    for (int s2 = 128; s2 > 0; s2 >>= 1) {
      if (t < s2) red[t] += red[t + s2];
      __syncthreads();
    }
    if (t == 0) tot[q] = red[0];
    __syncthreads();
  }
  if (t == 0) {
    const float q = DECAYF, al = ALPHA;
    float bbv = bb[0];
    float sumkeyf2 = tot[0] + 2.f * tot[9] + 2048.f * bbv;
    float cross = q * (tot[1] + tot[10]) + al * (tot[2] + 2.f * tot[11] + bbv * tot[12]);
    float sumq2 = q*q * tot[3] + 2.f*q*al * (tot[4] + tot[6])
                + al*al * (tot[5] + 2.f * tot[7] + bbv * tot[8]);
    out[524288] = (0.25f / (2048.0f * 65536.0f)) * (sumkeyf2 - 2.f * cross + sumq2);
  }
}

extern "C" void kernel_launch(void* const* d_in, const int* in_sizes, int n_in,
                              void* d_out, int out_size, void* d_ws, size_t ws_size,
                              hipStream_t stream) {
  const float* x    = (const float*)d_in[0];
  const float* u    = (const float*)d_in[1];
  const float* Wm   = (const float*)d_in[2];
  const float* bmap = (const float*)d_in[3];
  const float* pw   = (const float*)d_in[4];
  const float* pwB  = (const float*)d_in[5];
  const float* cen  = (const float*)d_in[6];
  float* out = (float*)d_out;
  float* ws  = (float*)d_ws;

  float* S_      = ws + OFF_S;
  float* Xsum    = ws + OFF_XSUM;
  float* G       = ws + OFF_G;
  float* M       = ws + OFF_M;
  float* Wb      = ws + OFF_WB;
  float* bb      = ws + OFF_BB;
  float* gsum    = ws + OFF_BB + 1;
  float* sumresp = ws + OFF_SUMR;
  float* A       = ws + OFF_A;
  float* CC0     = ws + OFF_CC0;
  float* RR      = ws + OFF_RR;
  unsigned int* cnt = (unsigned int*)(ws + OFF_CNT);
  float* cb      = ws + OFF_CB;
  int*   tslot   = (int*)(ws + OFF_TSLOT);
  float* resp    = ws + OFF_RESP;
  float* AG      = ws + OFF_AG;
  float* MA      = ws + OFF_MA;
  float* AGA     = ws + OFF_AGA;
  float* AWb     = ws + OFF_AWB;
  int*   che     = (int*)(ws + OFF_CHE);
  int*   chb     = (int*)(ws + OFF_CHB);
  int*   nch     = (int*)(ws + OFF_NCH);
  float* y       = ws + OFF_Y;
  float* cnew    = ws + OFF_CNEW;
  float* scratch = ws + OFF_CNEW;     // k_G3/k_M3/k_CCp partials (sequential reuse)
  int*   tokidx  = (int*)(ws + OFF_TIDX);
  float* tokr    = ws + OFF_TOKR;
  u16*   wth     = (u16*)(ws + OFF_WTH);
  u16*   wtl     = (u16*)(ws + OFF_WTL);
  u16*   cenh    = (u16*)(ws + OFF_CENH);
  u16*   cenl    = (u16*)(ws + OFF_CENL);

  bool fast = ws_size >= (size_t)WS_FAST_END * sizeof(float);
  bool full = ws_size >= (size_t)WS_FULL_END * sizeof(float);

  hipMemsetAsync(d_ws, 0, ZFLOATS * sizeof(float), stream);

  k_bb<<<4, 256, 0, stream>>>(bmap, bb);
  k_S<<<dim3(8, 16), 256, 0, stream>>>(x, S_);
  k_xsum<<<32, 256, 0, stream>>>(x, Xsum);
  if (fast) {
    k_Tw<<<2048, 256, 0, stream>>>(Wm, wth, wtl, full ? 1 : 0);
    k_G3<<<dim3(64, 10), 256, 0, stream>>>(wth, scratch);
  } else {
    k_Gslow<<<dim3(64, 10), 256, 0, stream>>>(Wm, scratch);
  }
  k_Gred<<<dim3(16, 10), 256, 0, stream>>>(scratch, G);
  if (full) {
    k_Tc<<<2048, 256, 0, stream>>>(cen, cenh, cenl);
    k_M3<<<dim3(128, 4), 256, 0, stream>>>(cenh, cenl, wth, wtl, scratch);
    k_Mred<<<dim3(64, 2), 256, 0, stream>>>(scratch, M);
  } else {
    k_M<<<dim3(256, 4), 256, 0, stream>>>(cen, Wm, scratch);
    k_Mred<<<dim3(64, 4), 256, 0, stream>>>(scratch, M);
  }
  k_CCp<<<512, 256, 0, stream>>>(cen, bmap, scratch, cb);
  k_CCred<<<128, 256, 0, stream>>>(scratch, CC0);
  k_Wb<<<256, 256, 0, stream>>>(bmap, Wm, Wb);
  k_y<<<dim3(32, 4), 256, 0, stream>>>(x, pw, y);
  k_resp<<<2048, 64, 0, stream>>>(x, u, M, CC0, cb, resp);
  k_route<<<8, 256, 0, stream>>>(resp, cnt, tokidx, tokr, tslot);
  k_A2<<<dim3(8, 4), 256, 0, stream>>>(resp, x, A);
  k_sr<<<8, 256, 0, stream>>>(resp, sumresp);
  k_RR2<<<8, 256, 0, stream>>>(resp, RR);
  k_plan<<<1, 256, 0, stream>>>(cnt, che, chb, nch);
  k_ag<<<64, 256, 0, stream>>>(A, G, Wb, AG, AWb);
  k_small64<<<64, 256, 0, stream>>>(M, A, AG, MA, AGA);
  k_cnew<<<1024, 256, 0, stream>>>(A, sumresp, cen, bmap, Wm, cnew);
  k_bias<<<2048, 256, 0, stream>>>(pwB, out);
  k_sA<<<dim3(SA_GRIDX, 2), 256, 0, stream>>>(che, chb, nch, cnt, tokidx, tokr,
                                              tslot, y, cnew, out);
  k_gs<<<64, 256, 0, stream>>>(G, S_, gsum);
  k_finalize<<<1, 256, 0, stream>>>(gsum, M, A, AG, CC0, RR, MA, AGA, Xsum, Wb,
                                    bb, sumresp, cb, AWb, out);
}

// Round 8
// 438.880 us; speedup vs baseline: 1.0480x; 1.0480x over previous
//
#include <hip/hip_runtime.h>
#include <hip/hip_bf16.h>

// Problem dims
constexpr int N_TOK = 2048;   // T*B
constexpr int C_    = 256;    // in features (== R == OUT)
constexpr int NE    = 64;     // experts
constexpr int D_    = 65536;  // R*OUT centroid dim
constexpr float DECAYF = 0.999f;
constexpr float OMD    = 0.001f;
constexpr float ALPHA  = OMD / 2048.0f;   // (1-decay)/N
constexpr float RTHRESH = 1e-5f;
constexpr int CHMAX = 8448;
constexpr int SA_GRIDX = 512;

using bf16x8 = __attribute__((ext_vector_type(8))) short;
using f32x4  = __attribute__((ext_vector_type(4))) float;
using u16 = unsigned short;

// ---------- workspace layout (float offsets) ----------
constexpr size_t OFF_S     = 0;        // 65536  (S no longer materialized; region spare)
constexpr size_t OFF_XSUM  = 65536;    // 256
constexpr size_t OFF_G     = 65792;    // 65536  G = W^T W (full)
constexpr size_t OFF_M     = 131328;   // 16384  M = cen @ W
constexpr size_t OFF_WB    = 147712;   // 256    Wb = b^T W
constexpr size_t OFF_BB    = 147968;   // 16     bb[0] = ||b||^2 ; bb[1] = gsum
constexpr size_t OFF_SUMR  = 147984;   // 64     sum_n resp
constexpr size_t OFF_A     = 148048;   // 16384  A = resp^T X
constexpr size_t OFF_CC0   = 164432;   // 4096   cen cen^T
constexpr size_t OFF_RR    = 168528;   // 4096   resp^T resp
constexpr size_t OFF_CNT   = 172624;   // 64     per-expert token counts (uint)
constexpr size_t OFF_CN2   = 172688;   // 64     (unused; cn2 == diag(CC0))
constexpr size_t OFF_CB    = 172752;   // 64
constexpr size_t OFF_TSLOT = 172816;   // 2048   per-token writer count (int)
constexpr size_t ZFLOATS   = 174864;
// overwritten-before-read zone:
constexpr size_t OFF_RESP  = 174864;   // 131072
constexpr size_t OFF_AG    = 174864;   // 16384 (overlay after resp dead)
constexpr size_t OFF_MA    = 191248;   // 4096
constexpr size_t OFF_AGA   = 195344;   // 4096
constexpr size_t OFF_AWB   = 199440;   // 64
constexpr size_t OFF_CHE   = 199504;   // 8448
constexpr size_t OFF_CHB   = 207952;   // 8448
constexpr size_t OFF_NCH   = 216400;   // 16
constexpr size_t OFF_Y     = 305936;   // 524288 y = X @ pw^T
constexpr size_t OFF_CNEW  = 830224;   // 4194304 ; also k_M partials (256*16384, exact fit)
constexpr size_t OFF_TIDX  = 5024528;  // 131072 (int)
constexpr size_t OFF_TOKR  = 5155600;  // 131072
// ---- bf16 + scratch extension. SIZE AUDIT (R2/R4 overlap lesson):
//   bf16[256][65536] = 16,777,216 u16 = 8,388,608 floats
constexpr size_t OFF_WTH   = 5286672;               // + 8,388,608 -> 13,675,280
constexpr size_t OFF_SCG   = 13675280;              // k_G3 partials, 2,621,440
constexpr size_t OFF_SCC   = 16296720;              // k_CCp partials, 2,097,152
constexpr size_t WS_FAST2_END = 18393872;           // 73.6 MB (R6 fill counter: ws = 256 MiB)

__device__ __forceinline__ unsigned pack_bf2(float a, float b) {
  __hip_bfloat16 ha = __float2bfloat16(a), hb = __float2bfloat16(b);
  unsigned short ua = *reinterpret_cast<unsigned short*>(&ha);
  unsigned short ub = *reinterpret_cast<unsigned short*>(&hb);
  return (unsigned)ua | ((unsigned)ub << 16);
}

// ---------------- bb[0] = ||b||^2 ----------------
__global__ __launch_bounds__(256) void k_bb(const float* __restrict__ bmap, float* __restrict__ bb) {
  int base = blockIdx.x * 16384 + threadIdx.x;
  float s = 0.f;
  for (int q = 0; q < 64; q++) { float v = bmap[base + q * 256]; s = fmaf(v, v, s); }
  __shared__ float red[256];
  red[threadIdx.x] = s;
  __syncthreads();
  for (int k = 128; k > 0; k >>= 1) {
    if (threadIdx.x < k) red[threadIdx.x] += red[threadIdx.x + k];
    __syncthreads();
  }
  if (threadIdx.x == 0) atomicAdd(&bb[0], red[0]);
}

// ======== generic 64x64 gram-style tile (A2 / RR2) ========
template<int KCHUNK>
__device__ __forceinline__ void gemm_tt_tile(
    const float* __restrict__ Aop, int lda, int ca,
    const float* __restrict__ Bop, int ldb, int cb,
    int d0, float* __restrict__ Out, int ldo, int ro, int co) {
  __shared__ float Wa[32][68], Wb[32][68];
  int t = threadIdx.x;
  int tx = t & 15, ty = t >> 4;
  int lr = t >> 3, lc = (t & 7) * 8;
  float acc[4][4] = {};
  for (int dk = 0; dk < KCHUNK; dk += 32) {
    const float* Arow = &Aop[(size_t)(d0 + dk + lr) * lda + ca];
    const float* Brow = &Bop[(size_t)(d0 + dk + lr) * ldb + cb];
    float4 a0 = *(const float4*)&Arow[lc];
    float4 a1 = *(const float4*)&Arow[lc + 4];
    float4 b0 = *(const float4*)&Brow[lc];
    float4 b1 = *(const float4*)&Brow[lc + 4];
    __syncthreads();
    *(float4*)&Wa[lr][lc]     = a0;
    *(float4*)&Wa[lr][lc + 4] = a1;
    *(float4*)&Wb[lr][lc]     = b0;
    *(float4*)&Wb[lr][lc + 4] = b1;
    __syncthreads();
    #pragma unroll
    for (int k = 0; k < 32; k++) {
      float4 ra4 = *(const float4*)&Wa[k][ty * 4];
      float4 rb4 = *(const float4*)&Wb[k][tx * 4];
      float ra[4] = {ra4.x, ra4.y, ra4.z, ra4.w};
      float rb[4] = {rb4.x, rb4.y, rb4.z, rb4.w};
      #pragma unroll
      for (int i = 0; i < 4; i++)
        #pragma unroll
        for (int j = 0; j < 4; j++)
          acc[i][j] = fmaf(ra[i], rb[j], acc[i][j]);
    }
  }
  #pragma unroll
  for (int i = 0; i < 4; i++)
    #pragma unroll
    for (int j = 0; j < 4; j++)
      atomicAdd(&Out[(size_t)(ro + ty * 4 + i) * ldo + co + tx * 4 + j], acc[i][j]);
}

// ==================== bf16 W-transpose (hi only; R5-proven) ====================
__global__ __launch_bounds__(256) void k_Tw(const float* __restrict__ W,
    u16* __restrict__ wth) {
  __shared__ float Ls[32][257];
  int t = threadIdx.x;
  int d0 = blockIdx.x * 32;
  int r = t >> 3, c8 = (t & 7) * 32;
  #pragma unroll
  for (int q = 0; q < 8; q++) {
    float4 v = *(const float4*)&W[(size_t)(d0 + r) * 256 + c8 + q * 4];
    Ls[r][c8 + q * 4 + 0] = v.x; Ls[r][c8 + q * 4 + 1] = v.y;
    Ls[r][c8 + q * 4 + 2] = v.z; Ls[r][c8 + q * 4 + 3] = v.w;
  }
  __syncthreads();
  int dq = (t & 3) * 8;
  #pragma unroll
  for (int pQ = 0; pQ < 4; pQ++) {
    int c = pQ * 64 + (t >> 2);
    unsigned hw[4];
    #pragma unroll
    for (int q = 0; q < 4; q++)
      hw[q] = pack_bf2(Ls[dq + 2 * q][c], Ls[dq + 2 * q + 1][c]);
    size_t o = (size_t)c * 65536 + d0 + dq;
    *(uint4*)&wth[o] = make_uint4(hw[0], hw[1], hw[2], hw[3]);
  }
}

// ==================== k_G3: G = Wt_hi Wt_hi^T via MFMA (R5/R6-proven) ========
__global__ __launch_bounds__(256) void k_G3(const u16* __restrict__ wth,
    float* __restrict__ part) {
  int kb = blockIdx.x;
  int p = blockIdx.y;
  int ti = 0, rem0 = p;
  while (rem0 >= 4 - ti) { rem0 -= 4 - ti; ti++; }
  int tj = ti + rem0;
  bool two = (ti != tj);
  const u16* srcA = wth + (size_t)(ti * 64) * 65536;
  const u16* srcB = wth + (size_t)(tj * 64) * 65536;
  __shared__ __align__(16) u16 Ta[8 * 68 * 8], Tb[8 * 68 * 8];
  int t = threadIdx.x, l = t & 63, w = t >> 6;
  int m0 = w * 16, lm = l & 15, g = l >> 4;
  int scol = t >> 3, skseg = t & 7;
  f32x4 acc[4] = {};
  for (int cc = 0; cc < 16; cc++) {
    int k0 = kb * 1024 + cc * 64;
    __syncthreads();   // protect previous chunk's frag reads
    {
      uint4 a0 = *(const uint4*)(srcA + (size_t)scol * 65536 + k0 + skseg * 8);
      uint4 a1 = *(const uint4*)(srcA + (size_t)(scol + 32) * 65536 + k0 + skseg * 8);
      *(uint4*)(Ta + (skseg * 68 + scol) * 8) = a0;
      *(uint4*)(Ta + (skseg * 68 + scol + 32) * 8) = a1;
      if (two) {
        uint4 b0 = *(const uint4*)(srcB + (size_t)scol * 65536 + k0 + skseg * 8);
        uint4 b1 = *(const uint4*)(srcB + (size_t)(scol + 32) * 65536 + k0 + skseg * 8);
        *(uint4*)(Tb + (skseg * 68 + scol) * 8) = b0;
        *(uint4*)(Tb + (skseg * 68 + scol + 32) * 8) = b1;
      }
    }
    __syncthreads();
    const u16* TBp = two ? Tb : Ta;
    #pragma unroll
    for (int ks = 0; ks < 2; ks++) {
      int kq = ks * 4 + g;
      bf16x8 av = *(const bf16x8*)(Ta + (kq * 68 + m0 + lm) * 8);
      #pragma unroll
      for (int j = 0; j < 4; j++) {
        bf16x8 bv = *(const bf16x8*)(TBp + (kq * 68 + j * 16 + lm) * 8);
        acc[j] = __builtin_amdgcn_mfma_f32_16x16x32_bf16(av, bv, acc[j], 0, 0, 0);
      }
    }
  }
  // C/D layout: col = lane&15, row = (lane>>4)*4 + reg  [m89-verified]
  float* pp = &part[((size_t)p * 64 + kb) * 4096];
  #pragma unroll
  for (int j = 0; j < 4; j++)
    #pragma unroll
    for (int r = 0; r < 4; r++)
      pp[(m0 + (l >> 4) * 4 + r) * 64 + j * 16 + lm] = acc[j][r];
}

// ---- fallback G (R1-proven: fused convert, partials) --
__global__ __launch_bounds__(256) void k_Gslow(const float* __restrict__ W,
    float* __restrict__ part) {
  int p = blockIdx.y;
  int ti = 0, rem0 = p;
  while (rem0 >= 4 - ti) { rem0 -= 4 - ti; ti++; }
  int tj = ti + rem0;
  int c1 = ti * 64, c2 = tj * 64;
  int d0 = blockIdx.x * 1024;
  __shared__ unsigned short Wat[64][40], Wbt[64][40];
  int t = threadIdx.x;
  int h = t >> 7;
  int rem = t & 127;
  int k2 = rem >> 3;
  int c4b = rem & 7;
  int cbase = h ? c2 : c1;
  unsigned short (*dst)[40] = h ? Wbt : Wat;
  int l = t & 63, w = t >> 6;
  int m0 = w * 16;
  int lm = l & 15, q8 = (l >> 4) * 8;
  f32x4 acc[4] = {};
  for (int dk = 0; dk < 1024; dk += 32) {
    __syncthreads();
    #pragma unroll
    for (int it = 0; it < 2; it++) {
      int c4 = c4b + it * 8;
      const float* rp = &W[(size_t)(d0 + dk + k2 * 2) * C_ + cbase + c4 * 4];
      float4 g0 = *(const float4*)rp;
      float4 g1 = *(const float4*)(rp + C_);
      *(unsigned*)&dst[c4 * 4 + 0][k2 * 2] = pack_bf2(g0.x, g1.x);
      *(unsigned*)&dst[c4 * 4 + 1][k2 * 2] = pack_bf2(g0.y, g1.y);
      *(unsigned*)&dst[c4 * 4 + 2][k2 * 2] = pack_bf2(g0.z, g1.z);
      *(unsigned*)&dst[c4 * 4 + 3][k2 * 2] = pack_bf2(g0.w, g1.w);
    }
    __syncthreads();
    bf16x8 av = *(const bf16x8*)&Wat[m0 + lm][q8];
    #pragma unroll
    for (int j = 0; j < 4; j++) {
      bf16x8 bv = *(const bf16x8*)&Wbt[j * 16 + lm][q8];
      acc[j] = __builtin_amdgcn_mfma_f32_16x16x32_bf16(av, bv, acc[j], 0, 0, 0);
    }
  }
  float* pp = &part[((size_t)p * 64 + blockIdx.x) * 4096];
  #pragma unroll
  for (int j = 0; j < 4; j++)
    #pragma unroll
    for (int r = 0; r < 4; r++)
      pp[(m0 + (l >> 4) * 4 + r) * 64 + j * 16 + lm] = acc[j][r];
}

// ---- separate reduce kernels (fallback path only) ----
__global__ __launch_bounds__(256) void k_Gred(const float* __restrict__ part,
    float* __restrict__ G) {
  int p = blockIdx.y;
  int ti = 0, rem0 = p;
  while (rem0 >= 4 - ti) { rem0 -= 4 - ti; ti++; }
  int tj = ti + rem0;
  int i = blockIdx.x * 256 + threadIdx.x;
  const float* base = part + (size_t)p * 64 * 4096 + i;
  float s = 0.f;
  for (int kb = 0; kb < 64; kb++) s += base[(size_t)kb * 4096];
  int r = i >> 6, c = i & 63;
  G[(ti * 64 + r) * C_ + tj * 64 + c] = s;
  if (ti != tj) G[(tj * 64 + c) * C_ + ti * 64 + r] = s;
}

__global__ __launch_bounds__(256) void k_Mred(const float* __restrict__ mpart,
    float* __restrict__ M) {
  int i = blockIdx.x * 256 + threadIdx.x;
  int kb0 = blockIdx.y * 64;
  float s = 0.f;
  #pragma unroll 8
  for (int kb = 0; kb < 64; kb++) s += mpart[(size_t)(kb0 + kb) * 16384 + i];
  atomicAdd(&M[i], s);
}

__global__ __launch_bounds__(256) void k_CCred(const float* __restrict__ part,
    float* __restrict__ CC0) {
  int i = (blockIdx.x & 15) * 256 + threadIdx.x;
  int kb0 = (blockIdx.x >> 4) * 64;
  float s = 0.f;
  #pragma unroll 8
  for (int kb = 0; kb < 64; kb++) s += part[(size_t)(kb0 + kb) * 4096 + i];
  atomicAdd(&CC0[i], s);
}

// ---- combined reduce (fast2 path): Gred(160) + Mred(256) + CCred(128) ----
__global__ __launch_bounds__(256) void k_redAll(const float* __restrict__ gp,
    const float* __restrict__ mp, const float* __restrict__ cp,
    float* __restrict__ G, float* __restrict__ M, float* __restrict__ CC0) {
  int bx = blockIdx.x;
  if (bx < 160) {
    int p = bx / 16, ib = bx % 16;
    int ti = 0, rem0 = p;
    while (rem0 >= 4 - ti) { rem0 -= 4 - ti; ti++; }
    int tj = ti + rem0;
    int i = ib * 256 + threadIdx.x;
    const float* base = gp + (size_t)p * 64 * 4096 + i;
    float s = 0.f;
    for (int kb = 0; kb < 64; kb++) s += base[(size_t)kb * 4096];
    int r = i >> 6, c = i & 63;
    G[(ti * 64 + r) * C_ + tj * 64 + c] = s;
    if (ti != tj) G[(tj * 64 + c) * C_ + ti * 64 + r] = s;
  } else if (bx < 416) {
    int idx = bx - 160;
    int i = (idx & 63) * 256 + threadIdx.x;
    int kb0 = (idx >> 6) * 64;
    float s = 0.f;
    #pragma unroll 8
    for (int kb = 0; kb < 64; kb++) s += mp[(size_t)(kb0 + kb) * 16384 + i];
    atomicAdd(&M[i], s);
  } else {
    int idx = bx - 416;
    int i = (idx & 15) * 256 + threadIdx.x;
    int kb0 = (idx >> 4) * 64;
    float s = 0.f;
    #pragma unroll 8
    for (int kb = 0; kb < 64; kb++) s += cp[(size_t)(kb0 + kb) * 4096 + i];
    atomicAdd(&CC0[i], s);
  }
}

// ==================== shared pipeline ====================

// ---- A = resp^T X ----
__global__ __launch_bounds__(256) void k_A2(const float* __restrict__ resp,
    const float* __restrict__ x, float* __restrict__ A) {
  gemm_tt_tile<256>(resp, NE, 0, x, C_, blockIdx.y * 64, blockIdx.x * 256,
                    A, C_, 0, blockIdx.y * 64);
}

// ---- RR = resp^T resp ----
__global__ __launch_bounds__(256) void k_RR2(const float* __restrict__ resp,
    float* __restrict__ RR) {
  gemm_tt_tile<256>(resp, NE, 0, resp, NE, 0, blockIdx.x * 256, RR, NE, 0, 0);
}

// ---- sumresp ----
__global__ __launch_bounds__(256) void k_sr(const float* __restrict__ resp,
    float* __restrict__ sumresp) {
  int e = threadIdx.x & 63, part = threadIdx.x >> 6;
  int n0 = blockIdx.x * 256 + part * 64;
  float s = 0.f;
  for (int n = n0; n < n0 + 64; n++) s += resp[n * NE + e];
  __shared__ float red[256];
  red[threadIdx.x] = s;
  __syncthreads();
  if (part == 0)
    atomicAdd(&sumresp[e], red[e] + red[64 + e] + red[128 + e] + red[192 + e]);
}

// ---------------- Xsum ----------------
__global__ __launch_bounds__(256) void k_xsum(const float* __restrict__ x, float* __restrict__ xsum) {
  int n0 = blockIdx.x * 64;
  int c = threadIdx.x;
  float s = 0.f;
  for (int n = 0; n < 64; n++) s += x[(n0 + n) * C_ + c];
  atomicAdd(&xsum[c], s);
}

// ---- M = cen @ W fp32 (R3/R5/R6-proven; logits precision-critical). ksplit 256x256 ----
__global__ __launch_bounds__(256) void k_M(const float* __restrict__ cen,
    const float* __restrict__ W, float* __restrict__ mpart) {
  int kb = blockIdx.x;
  int c0 = blockIdx.y * 64;
  int d0 = kb * 256;
  __shared__ float As[32][68];
  __shared__ float Bs[32][68];
  int t = threadIdx.x;
  int tx = t & 15, ty = t >> 4;
  int e = t >> 2, dg = t & 3;
  int lr = t >> 3, lc = (t & 7) * 8;
  float acc[4][4] = {};
  for (int dk = 0; dk < 256; dk += 32) {
    const float* cr = &cen[(size_t)e * D_ + d0 + dk];
    float4 cv0 = *(const float4*)&cr[dg * 4];
    float4 cv1 = *(const float4*)&cr[16 + dg * 4];
    const float* wr = &W[(size_t)(d0 + dk + lr) * C_ + c0];
    float4 w0 = *(const float4*)&wr[lc];
    float4 w1 = *(const float4*)&wr[lc + 4];
    __syncthreads();
    As[dg * 4 + 0][e] = cv0.x; As[dg * 4 + 1][e] = cv0.y;
    As[dg * 4 + 2][e] = cv0.z; As[dg * 4 + 3][e] = cv0.w;
    As[16 + dg * 4 + 0][e] = cv1.x; As[16 + dg * 4 + 1][e] = cv1.y;
    As[16 + dg * 4 + 2][e] = cv1.z; As[16 + dg * 4 + 3][e] = cv1.w;
    *(float4*)&Bs[lr][lc]     = w0;
    *(float4*)&Bs[lr][lc + 4] = w1;
    __syncthreads();
    #pragma unroll 8
    for (int k = 0; k < 32; k++) {
      float4 ra4 = *(const float4*)&As[k][ty * 4];
      float4 rb4 = *(const float4*)&Bs[k][tx * 4];
      float ra[4] = {ra4.x, ra4.y, ra4.z, ra4.w};
      float rb[4] = {rb4.x, rb4.y, rb4.z, rb4.w};
      #pragma unroll
      for (int i = 0; i < 4; i++)
        #pragma unroll
        for (int j = 0; j < 4; j++)
          acc[i][j] = fmaf(ra[i], rb[j], acc[i][j]);
    }
  }
  float* pp = &mpart[(size_t)kb * 16384];
  #pragma unroll
  for (int i = 0; i < 4; i++)
    *(float4*)&pp[(ty * 4 + i) * C_ + c0 + tx * 4] = *(float4*)&acc[i][0];
}

// ---- CC partials + cb: 512 blocks x 128-d chunk ----
__global__ __launch_bounds__(256) void k_CCp(const float* __restrict__ cen,
    const float* __restrict__ bmap, float* __restrict__ part,
    float* __restrict__ cb) {
  int d0 = blockIdx.x * 128;
  __shared__ float cs[32][68];
  __shared__ float red[256];
  int t = threadIdx.x;
  int e = t >> 2, dg = t & 3;
  int tx = t & 15, ty = t >> 4;
  float acc[4][4] = {};
  float cbp = 0.f;
  for (int dk = 0; dk < 128; dk += 32) {
    const float* cr = &cen[(size_t)e * D_ + d0 + dk];
    float4 v0 = *(const float4*)&cr[dg * 4];
    float4 v1 = *(const float4*)&cr[16 + dg * 4];
    const float* br = &bmap[d0 + dk];
    float4 b0 = *(const float4*)&br[dg * 4];
    float4 b1 = *(const float4*)&br[16 + dg * 4];
    cbp += v0.x * b0.x + v0.y * b0.y + v0.z * b0.z + v0.w * b0.w
         + v1.x * b1.x + v1.y * b1.y + v1.z * b1.z + v1.w * b1.w;
    __syncthreads();
    cs[dg * 4 + 0][e] = v0.x; cs[dg * 4 + 1][e] = v0.y;
    cs[dg * 4 + 2][e] = v0.z; cs[dg * 4 + 3][e] = v0.w;
    cs[16 + dg * 4 + 0][e] = v1.x; cs[16 + dg * 4 + 1][e] = v1.y;
    cs[16 + dg * 4 + 2][e] = v1.z; cs[16 + dg * 4 + 3][e] = v1.w;
    __syncthreads();
    #pragma unroll
    for (int k = 0; k < 32; k++) {
      float4 ra4 = *(const float4*)&cs[k][ty * 4];
      float4 rb4 = *(const float4*)&cs[k][tx * 4];
      float ra[4] = {ra4.x, ra4.y, ra4.z, ra4.w};
      float rb[4] = {rb4.x, rb4.y, rb4.z, rb4.w};
      #pragma unroll
      for (int i = 0; i < 4; i++)
        #pragma unroll
        for (int j = 0; j < 4; j++)
          acc[i][j] = fmaf(ra[i], rb[j], acc[i][j]);
    }
  }
  float* pp = &part[(size_t)blockIdx.x * 4096];
  #pragma unroll
  for (int i = 0; i < 4; i++)
    *(float4*)&pp[(ty * 4 + i) * 64 + tx * 4] = *(float4*)&acc[i][0];
  red[t] = cbp;
  __syncthreads();
  if (t < 64)
    atomicAdd(&cb[t], red[t * 4] + red[t * 4 + 1] + red[t * 4 + 2] + red[t * 4 + 3]);
}

// ---------------- Wb[c] = sum_d b[d] W[d,c] (skip all-zero b chunks) ----------
__global__ __launch_bounds__(256) void k_Wb(const float* __restrict__ bmap,
    const float* __restrict__ W, float* __restrict__ Wb) {
  int d0 = blockIdx.x * 256;
  int c = threadIdx.x;
  __shared__ float bs[256];
  __shared__ int any;
  if (c == 0) any = 0;
  __syncthreads();
  float bv = bmap[d0 + c];
  bs[c] = bv;
  if (bv != 0.f) any = 1;
  __syncthreads();
  if (any == 0) return;
  float s = 0.f;
  for (int d = 0; d < 256; d++) s = fmaf(bs[d], W[(size_t)(d0 + d) * C_ + c], s);
  atomicAdd(&Wb[c], s);
}

// ---------------- y = X @ pw^T ----------------
__global__ __launch_bounds__(256) void k_y(const float* __restrict__ x,
    const float* __restrict__ pw, float* __restrict__ y) {
  int n0 = blockIdx.x * 64, k0 = blockIdx.y * 64;
  __shared__ float Xs[64][17], Ps[64][17];
  int t = threadIdx.x;
  int tx = t & 15, ty = t >> 4;
  int r = t >> 2, q4 = (t & 3) * 4;
  float acc[4][4] = {};
  for (int j0 = 0; j0 < 256; j0 += 16) {
    float4 va = *(const float4*)&x[(n0 + r) * C_ + j0 + q4];
    float4 vb = *(const float4*)&pw[(k0 + r) * C_ + j0 + q4];
    __syncthreads();
    Xs[r][q4] = va.x; Xs[r][q4+1] = va.y; Xs[r][q4+2] = va.z; Xs[r][q4+3] = va.w;
    Ps[r][q4] = vb.x; Ps[r][q4+1] = vb.y; Ps[r][q4+2] = vb.z; Ps[r][q4+3] = vb.w;
    __syncthreads();
    #pragma unroll
    for (int k = 0; k < 16; k++) {
      float ra[4], rb[4];
      #pragma unroll
      for (int i = 0; i < 4; i++) ra[i] = Xs[ty*4 + i][k];
      #pragma unroll
      for (int j = 0; j < 4; j++) rb[j] = Ps[tx*4 + j][k];
      #pragma unroll
      for (int i = 0; i < 4; i++)
        #pragma unroll
        for (int j = 0; j < 4; j++)
          acc[i][j] = fmaf(ra[i], rb[j], acc[i][j]);
    }
  }
  #pragma unroll
  for (int i = 0; i < 4; i++)
    #pragma unroll
    for (int j = 0; j < 4; j++)
      y[(n0 + ty*4 + i) * C_ + k0 + tx*4 + j] = acc[i][j];
}

// ---- gsum = sum_n x_n^T G x_n  (replaces k_S + k_gs: S only ever fed G.*S;
// computing tr(G X^T X) as (X@G) dot X removes the 524K-atomic S build) ----
__global__ __launch_bounds__(256) void k_gs2(const float* __restrict__ x,
    const float* __restrict__ G, float* __restrict__ gsum) {
  int n0 = blockIdx.x * 64, k0 = blockIdx.y * 64;
  __shared__ float Xs[64][17], Ps[64][17];
  __shared__ float red[256];
  int t = threadIdx.x;
  int tx = t & 15, ty = t >> 4;
  int r = t >> 2, q4 = (t & 3) * 4;
  float acc[4][4] = {};
  for (int j0 = 0; j0 < 256; j0 += 16) {
    float4 va = *(const float4*)&x[(n0 + r) * C_ + j0 + q4];
    float4 vb = *(const float4*)&G[(k0 + r) * C_ + j0 + q4];   // G symmetric
    __syncthreads();
    Xs[r][q4] = va.x; Xs[r][q4+1] = va.y; Xs[r][q4+2] = va.z; Xs[r][q4+3] = va.w;
    Ps[r][q4] = vb.x; Ps[r][q4+1] = vb.y; Ps[r][q4+2] = vb.z; Ps[r][q4+3] = vb.w;
    __syncthreads();
    #pragma unroll
    for (int k = 0; k < 16; k++) {
      float ra[4], rb[4];
      #pragma unroll
      for (int i = 0; i < 4; i++) ra[i] = Xs[ty*4 + i][k];
      #pragma unroll
      for (int j = 0; j < 4; j++) rb[j] = Ps[tx*4 + j][k];
      #pragma unroll
      for (int i = 0; i < 4; i++)
        #pragma unroll
        for (int j = 0; j < 4; j++)
          acc[i][j] = fmaf(ra[i], rb[j], acc[i][j]);
    }
  }
  // acc[i][j] = (X@G)[n0+ty*4+i][k0+tx*4+j]; dot with x at same positions
  float s = 0.f;
  #pragma unroll
  for (int i = 0; i < 4; i++) {
    float4 xv = *(const float4*)&x[(size_t)(n0 + ty*4 + i) * C_ + k0 + tx*4];
    s += acc[i][0]*xv.x + acc[i][1]*xv.y + acc[i][2]*xv.z + acc[i][3]*xv.w;
  }
  red[t] = s;
  __syncthreads();
  for (int k = 128; k > 0; k >>= 1) {
    if (t < k) red[t] += red[t + k];
    __syncthreads();
  }
  if (t == 0) atomicAdd(gsum, red[0]);
}

// ------- resp softmax (cn2 read from diag of CC0) --------
__global__ __launch_bounds__(64) void k_resp(const float* __restrict__ x,
    const float* __restrict__ u, const float* __restrict__ M,
    const float* __restrict__ CC0, const float* __restrict__ cb,
    float* __restrict__ resp) {
  int n = blockIdx.x;
  int e = threadIdx.x;
  __shared__ float xs[256];
  *(float4*)&xs[e * 4] = *(const float4*)&x[n * C_ + e * 4];
  __syncthreads();
  const float* Me = M + e * C_;
  float s = 0.f;
  #pragma unroll 8
  for (int j = 0; j < 256; j += 4) {
    float4 m4 = *(const float4*)&Me[j];
    s = fmaf(xs[j],   m4.x, s);
    s = fmaf(xs[j+1], m4.y, s);
    s = fmaf(xs[j+2], m4.z, s);
    s = fmaf(xs[j+3], m4.w, s);
  }
  float uu = u[n * NE + e];
  float g = -logf(-logf(uu));
  float logit = 2.0f * (s + cb[e]) - CC0[e * 65] + g;   // TAU == 1
  float m = logit;
  for (int off = 32; off > 0; off >>= 1) m = fmaxf(m, __shfl_xor(m, off));
  float ex = expf(logit - m);
  float sum = ex;
  for (int off = 32; off > 0; off >>= 1) sum += __shfl_xor(sum, off);
  resp[n * NE + e] = ex / sum;
}

// ------- routing (NO cap — r3 lesson) -------
__global__ __launch_bounds__(256) void k_route(const float* __restrict__ resp,
    unsigned int* __restrict__ cnt, int* __restrict__ tokidx,
    float* __restrict__ tokr, int* __restrict__ tslot) {
  int n = blockIdx.x * 256 + threadIdx.x;
  int s = 0;
  #pragma unroll 4
  for (int e = 0; e < NE; e++) {
    float r = resp[n * NE + e];
    if (r > RTHRESH) {
      unsigned pos = atomicAdd(&cnt[e], 1u);
      tokidx[e * 2048 + pos] = n;
      tokr[e * 2048 + pos] = r;
      s++;
    }
  }
  tslot[n] = s;
}

// ------- planner (parallel fill; R6-proven) -------
__global__ __launch_bounds__(256) void k_plan(const unsigned int* __restrict__ cnt,
    int* __restrict__ che, int* __restrict__ chb, int* __restrict__ nch) {
  __shared__ int cbase[65];
  __shared__ int ncs[64];
  int t = threadIdx.x;
  if (t < 64) ncs[t] = ((int)cnt[t] + 15) >> 4;
  __syncthreads();
  if (t == 0) {
    int s = 0;
    for (int e = 0; e < 64; e++) { cbase[e] = s; s += ncs[e]; }
    cbase[64] = s;
    nch[0] = s < CHMAX ? s : CHMAX;
  }
  __syncthreads();
  for (int e = 0; e < 64; e++) {
    int b0 = cbase[e], nc = cbase[e + 1] - b0;
    for (int i = t; i < nc; i += 256) {
      int idx = b0 + i;
      if (idx < CHMAX) { che[idx] = e; chb[idx] = i * 16; }
    }
  }
}

// ---------------- AG = A @ G, AWb ----------------
__global__ __launch_bounds__(256) void k_ag(const float* __restrict__ A,
    const float* __restrict__ G, const float* __restrict__ Wb,
    float* __restrict__ AG, float* __restrict__ AWb) {
  int e = blockIdx.x, c = threadIdx.x;
  float s = 0.f;
  for (int cp = 0; cp < C_; cp++) s = fmaf(A[e * C_ + cp], G[cp * C_ + c], s);
  AG[e * C_ + c] = s;
  float p = A[e * C_ + c] * Wb[c];
  __shared__ float red[256];
  red[c] = p;
  __syncthreads();
  for (int k = 128; k > 0; k >>= 1) {
    if (c < k) red[c] += red[c + k];
    __syncthreads();
  }
  if (c == 0) AWb[e] = red[0];
}

// ---------------- MA = M A^T, AGA = AG A^T ----------------
__global__ __launch_bounds__(256) void k_small64(const float* __restrict__ M,
    const float* __restrict__ A, const float* __restrict__ AG,
    float* __restrict__ MA, float* __restrict__ AGA) {
  int e = blockIdx.x;
  int f = threadIdx.x >> 2, q = threadIdx.x & 3;
  float s1 = 0.f, s2 = 0.f;
  for (int c = q * 64; c < q * 64 + 64; c++) {
    float a = A[f * C_ + c];
    s1 = fmaf(M[e * C_ + c], a, s1);
    s2 = fmaf(AG[e * C_ + c], a, s2);
  }
  __shared__ float r1[256], r2[256];
  r1[threadIdx.x] = s1; r2[threadIdx.x] = s2;
  __syncthreads();
  if (q == 0) {
    MA[e * NE + f]  = r1[f*4] + r1[f*4+1] + r1[f*4+2] + r1[f*4+3];
    AGA[e * NE + f] = r2[f*4] + r2[f*4+1] + r2[f*4+2] + r2[f*4+3];
  }
}

// ------- cnew[e,d] = decay*cen + alpha*(A_e.W_d + sr_e*b_d)  [MFMA, R6-proven]
__global__ __launch_bounds__(256) void k_cnew(const float* __restrict__ A,
    const float* __restrict__ sumresp, const float* __restrict__ cen,
    const float* __restrict__ bmap, const float* __restrict__ W,
    float* __restrict__ cnew) {
  int d0 = blockIdx.x * 64;
  __shared__ __align__(16) u16 Abf[64 * 264];
  __shared__ __align__(16) u16 Wt[64 * 264];
  __shared__ float srs[64];
  int t = threadIdx.x, l = t & 63;
  int m0 = (t >> 6) * 16, lm = l & 15, g = l >> 4;
  {
    int e = t >> 2, c0 = (t & 3) * 64;
    const float* ar = &A[e * C_ + c0];
    u16* dst = &Abf[e * 264 + c0];
    #pragma unroll
    for (int q = 0; q < 8; q++) {
      float4 v0 = *(const float4*)&ar[q * 8];
      float4 v1 = *(const float4*)&ar[q * 8 + 4];
      *(uint4*)&dst[q * 8] = make_uint4(pack_bf2(v0.x, v0.y), pack_bf2(v0.z, v0.w),
                                        pack_bf2(v1.x, v1.y), pack_bf2(v1.z, v1.w));
    }
    int r = t >> 2;
    const float* wr = &W[(size_t)(d0 + r) * C_ + c0];
    u16* wdst = &Wt[r * 264 + c0];
    #pragma unroll
    for (int q = 0; q < 8; q++) {
      float4 v0 = *(const float4*)&wr[q * 8];
      float4 v1 = *(const float4*)&wr[q * 8 + 4];
      *(uint4*)&wdst[q * 8] = make_uint4(pack_bf2(v0.x, v0.y), pack_bf2(v0.z, v0.w),
                                         pack_bf2(v1.x, v1.y), pack_bf2(v1.z, v1.w));
    }
    if (t < 64) srs[t] = sumresp[t];
  }
  __syncthreads();
  f32x4 acc[4] = {};
  #pragma unroll
  for (int kk = 0; kk < 8; kk++) {
    bf16x8 av = *(const bf16x8*)&Abf[(m0 + lm) * 264 + kk * 32 + g * 8];
    #pragma unroll
    for (int j = 0; j < 4; j++) {
      bf16x8 bv = *(const bf16x8*)&Wt[(j * 16 + lm) * 264 + kk * 32 + g * 8];
      acc[j] = __builtin_amdgcn_mfma_f32_16x16x32_bf16(av, bv, acc[j], 0, 0, 0);
    }
  }
  #pragma unroll
  for (int j = 0; j < 4; j++) {
    int d = d0 + j * 16 + lm;
    float bv = bmap[d];
    #pragma unroll
    for (int r = 0; r < 4; r++) {
      int e = m0 + g * 4 + r;
      size_t o = (size_t)e * D_ + d;
      cnew[o] = DECAYF * cen[o] + ALPHA * (acc[j][r] + srs[e] * bv);
    }
  }
}

// ---------------- out init with bias ----------------
__global__ __launch_bounds__(256) void k_bias(const float* __restrict__ pwB, float* __restrict__ out) {
  int idx = blockIdx.x * 256 + threadIdx.x;
  out[idx] = pwB[idx & 255];
}

// ------- stage A: dense grouped GEMM -------
__global__ __launch_bounds__(256) void k_sA(const int* __restrict__ che,
    const int* __restrict__ chb, const int* __restrict__ nch,
    const unsigned int* __restrict__ cnt, const int* __restrict__ tokidx,
    const float* __restrict__ tokr, const int* __restrict__ tslot,
    const float* __restrict__ y, const float* __restrict__ cnew,
    float* __restrict__ out) {
  int nchv = nch[0];
  int i0 = blockIdx.y * 128;
  __shared__ int nsh[16]; __shared__ float rsh[16]; __shared__ int wsh[16];
  __shared__ float Ys[16][260];
  __shared__ float Bs[32][132];
  int t = threadIdx.x;
  for (int ch = blockIdx.x; ch < nchv; ch += SA_GRIDX) {
    int e = che[ch], base = chb[ch];
    int c = (int)cnt[e];
    __syncthreads();
    if (t < 16) {
      int idx = base + t;
      if (idx < c) {
        int n = tokidx[e * 2048 + idx];
        nsh[t] = n; rsh[t] = tokr[e * 2048 + idx]; wsh[t] = tslot[n];
      } else { nsh[t] = 0; rsh[t] = 0.f; wsh[t] = 2; }
    }
    __syncthreads();
    {
      int row = t >> 4, c0 = (t & 15) * 16;
      const float* yr = &y[nsh[row] * C_ + c0];
      float4 v0 = *(const float4*)&yr[0];
      float4 v1 = *(const float4*)&yr[4];
      float4 v2 = *(const float4*)&yr[8];
      float4 v3 = *(const float4*)&yr[12];
      *(float4*)&Ys[row][c0]      = v0;
      *(float4*)&Ys[row][c0 + 4]  = v1;
      *(float4*)&Ys[row][c0 + 8]  = v2;
      *(float4*)&Ys[row][c0 + 12] = v3;
    }
    int tx = t & 31, ty = t >> 5;
    int br = t >> 1, bk = (t & 1) * 16;
    float acc[2][4] = {};
    for (int k0 = 0; k0 < 256; k0 += 32) {
      const float* Brow = &cnew[(size_t)e * D_ + (size_t)(i0 + br) * C_ + k0 + bk];
      float4 b0 = *(const float4*)&Brow[0];
      float4 b1 = *(const float4*)&Brow[4];
      float4 b2 = *(const float4*)&Brow[8];
      float4 b3 = *(const float4*)&Brow[12];
      __syncthreads();
      Bs[bk+0][br]  = b0.x; Bs[bk+1][br]  = b0.y; Bs[bk+2][br]  = b0.z; Bs[bk+3][br]  = b0.w;
      Bs[bk+4][br]  = b1.x; Bs[bk+5][br]  = b1.y; Bs[bk+6][br]  = b1.z; Bs[bk+7][br]  = b1.w;
      Bs[bk+8][br]  = b2.x; Bs[bk+9][br]  = b2.y; Bs[bk+10][br] = b2.z; Bs[bk+11][br] = b2.w;
      Bs[bk+12][br] = b3.x; Bs[bk+13][br] = b3.y; Bs[bk+14][br] = b3.z; Bs[bk+15][br] = b3.w;
      __syncthreads();
      #pragma unroll
      for (int kk = 0; kk < 32; kk++) {
        float a0 = Ys[ty*2 + 0][k0 + kk];
        float a1 = Ys[ty*2 + 1][k0 + kk];
        float4 bv = *(const float4*)&Bs[kk][tx*4];
        acc[0][0] = fmaf(a0, bv.x, acc[0][0]); acc[0][1] = fmaf(a0, bv.y, acc[0][1]);
        acc[0][2] = fmaf(a0, bv.z, acc[0][2]); acc[0][3] = fmaf(a0, bv.w, acc[0][3]);
        acc[1][0] = fmaf(a1, bv.x, acc[1][0]); acc[1][1] = fmaf(a1, bv.y, acc[1][1]);
        acc[1][2] = fmaf(a1, bv.z, acc[1][2]); acc[1][3] = fmaf(a1, bv.w, acc[1][3]);
      }
    }
    #pragma unroll
    for (int i = 0; i < 2; i++) {
      int tk = ty*2 + i;
      float r = rsh[tk];
      if (r == 0.f) continue;
      int n = nsh[tk];
      float* op = &out[n * C_ + i0 + tx*4];
      if (wsh[tk] == 1) {
        float4 cur = *(const float4*)op;
        cur.x += r * acc[i][0]; cur.y += r * acc[i][1];
        cur.z += r * acc[i][2]; cur.w += r * acc[i][3];
        *(float4*)op = cur;
      } else {
        atomicAdd(op + 0, r * acc[i][0]);
        atomicAdd(op + 1, r * acc[i][1]);
        atomicAdd(op + 2, r * acc[i][2]);
        atomicAdd(op + 3, r * acc[i][3]);
      }
    }
  }
}

// ---------------- loss assembly ----------------
__global__ __launch_bounds__(256) void k_finalize(
    const float* __restrict__ gsum, const float* __restrict__ M,
    const float* __restrict__ A, const float* __restrict__ AG,
    const float* __restrict__ CC0, const float* __restrict__ RR,
    const float* __restrict__ MA, const float* __restrict__ AGA,
    const float* __restrict__ Xsum, const float* __restrict__ Wb,
    const float* __restrict__ bb, const float* __restrict__ sr,
    const float* __restrict__ cb, const float* __restrict__ AWb,
    float* __restrict__ out) {
  int t = threadIdx.x;
  float a_gs = (t == 0) ? gsum[0] : 0.f;
  float a_am = 0.f, a_aag = 0.f;
  for (int i = t; i < 16384; i += 256) {
    float a = A[i];
    a_am  = fmaf(M[i], a, a_am);
    a_aag = fmaf(AG[i], a, a_aag);
  }
  float a_cc = 0.f, a_ma = 0.f, a_aga = 0.f, a_cbsr = 0.f, a_awbsr = 0.f, a_srsr = 0.f;
  for (int p = t; p < 4096; p += 256) {
    float r = RR[p];
    int e = p >> 6, f = p & 63;
    float srf = sr[f];
    a_cc    = fmaf(r, CC0[p], a_cc);
    a_ma    = fmaf(r, MA[p], a_ma);
    a_aga   = fmaf(r, AGA[p], a_aga);
    a_cbsr  = fmaf(r * cb[e], srf, a_cbsr);
    a_awbsr = fmaf(r * AWb[e], srf, a_awbsr);
    a_srsr  = fmaf(r * sr[e], srf, a_srsr);
  }
  float a_xw = Xsum[t] * Wb[t];
  float a_srcb = 0.f, a_srawb = 0.f, a_sr2 = 0.f;
  if (t < 64) { float s = sr[t]; a_srcb = s * cb[t]; a_srawb = s * AWb[t]; a_sr2 = s * s; }
  float v[13] = {a_gs, a_am, a_aag, a_cc, a_ma, a_aga, a_cbsr, a_awbsr, a_srsr,
                 a_xw, a_srcb, a_srawb, a_sr2};
  __shared__ float red[256];
  __shared__ float tot[13];
  for (int q = 0; q < 13; q++) {
    red[t] = v[q];
    __syncthreads();
    for (int s2 = 128; s2 > 0; s2 >>= 1) {
      if (t < s2) red[t] += red[t + s2];
      __syncthreads();
    }
    if (t == 0) tot[q] = red[0];
    __syncthreads();
  }
  if (t == 0) {
    const float q = DECAYF, al = ALPHA;
    float bbv = bb[0];
    float sumkeyf2 = tot[0] + 2.f * tot[9] + 2048.f * bbv;
    float cross = q * (tot[1] + tot[10]) + al * (tot[2] + 2.f * tot[11] + bbv * tot[12]);
    float sumq2 = q*q * tot[3] + 2.f*q*al * (tot[4] + tot[6])
                + al*al * (tot[5] + 2.f * tot[7] + bbv * tot[8]);
    out[524288] = (0.25f / (2048.0f * 65536.0f)) * (sumkeyf2 - 2.f * cross + sumq2);
  }
}

extern "C" void kernel_launch(void* const* d_in, const int* in_sizes, int n_in,
                              void* d_out, int out_size, void* d_ws, size_t ws_size,
                              hipStream_t stream) {
  const float* x    = (const float*)d_in[0];
  const float* u    = (const float*)d_in[1];
  const float* Wm   = (const float*)d_in[2];
  const float* bmap = (const float*)d_in[3];
  const float* pw   = (const float*)d_in[4];
  const float* pwB  = (const float*)d_in[5];
  const float* cen  = (const float*)d_in[6];
  float* out = (float*)d_out;
  float* ws  = (float*)d_ws;

  float* Xsum    = ws + OFF_XSUM;
  float* G       = ws + OFF_G;
  float* M       = ws + OFF_M;
  float* Wb      = ws + OFF_WB;
  float* bb      = ws + OFF_BB;
  float* gsum    = ws + OFF_BB + 1;
  float* sumresp = ws + OFF_SUMR;
  float* A       = ws + OFF_A;
  float* CC0     = ws + OFF_CC0;
  float* RR      = ws + OFF_RR;
  unsigned int* cnt = (unsigned int*)(ws + OFF_CNT);
  float* cb      = ws + OFF_CB;
  int*   tslot   = (int*)(ws + OFF_TSLOT);
  float* resp    = ws + OFF_RESP;
  float* AG      = ws + OFF_AG;
  float* MA      = ws + OFF_MA;
  float* AGA     = ws + OFF_AGA;
  float* AWb     = ws + OFF_AWB;
  int*   che     = (int*)(ws + OFF_CHE);
  int*   chb     = (int*)(ws + OFF_CHB);
  int*   nch     = (int*)(ws + OFF_NCH);
  float* y       = ws + OFF_Y;
  float* cnew    = ws + OFF_CNEW;
  float* scratch = ws + OFF_CNEW;     // fallback sequential-reuse scratch; fast2 M partials
  int*   tokidx  = (int*)(ws + OFF_TIDX);
  float* tokr    = ws + OFF_TOKR;
  u16*   wth     = (u16*)(ws + OFF_WTH);
  float* sc_g    = ws + OFF_SCG;
  float* sc_cc   = ws + OFF_SCC;

  bool fast2 = ws_size >= (size_t)WS_FAST2_END * sizeof(float);

  hipMemsetAsync(d_ws, 0, ZFLOATS * sizeof(float), stream);

  k_bb<<<4, 256, 0, stream>>>(bmap, bb);
  k_xsum<<<32, 256, 0, stream>>>(x, Xsum);
  if (fast2) {
    k_Tw<<<2048, 256, 0, stream>>>(Wm, wth);
    k_G3<<<dim3(64, 10), 256, 0, stream>>>(wth, sc_g);
    k_M<<<dim3(256, 4), 256, 0, stream>>>(cen, Wm, scratch);
    k_CCp<<<512, 256, 0, stream>>>(cen, bmap, sc_cc, cb);
    k_redAll<<<544, 256, 0, stream>>>(sc_g, scratch, sc_cc, G, M, CC0);
  } else {
    k_Gslow<<<dim3(64, 10), 256, 0, stream>>>(Wm, scratch);
    k_Gred<<<dim3(16, 10), 256, 0, stream>>>(scratch, G);
    k_M<<<dim3(256, 4), 256, 0, stream>>>(cen, Wm, scratch);
    k_Mred<<<dim3(64, 4), 256, 0, stream>>>(scratch, M);
    k_CCp<<<512, 256, 0, stream>>>(cen, bmap, scratch, cb);
    k_CCred<<<128, 256, 0, stream>>>(scratch, CC0);
  }
  k_Wb<<<256, 256, 0, stream>>>(bmap, Wm, Wb);
  k_y<<<dim3(32, 4), 256, 0, stream>>>(x, pw, y);
  k_gs2<<<dim3(32, 4), 256, 0, stream>>>(x, G, gsum);
  k_resp<<<2048, 64, 0, stream>>>(x, u, M, CC0, cb, resp);
  k_route<<<8, 256, 0, stream>>>(resp, cnt, tokidx, tokr, tslot);
  k_A2<<<dim3(8, 4), 256, 0, stream>>>(resp, x, A);
  k_sr<<<8, 256, 0, stream>>>(resp, sumresp);
  k_RR2<<<8, 256, 0, stream>>>(resp, RR);
  k_plan<<<1, 256, 0, stream>>>(cnt, che, chb, nch);
  k_ag<<<64, 256, 0, stream>>>(A, G, Wb, AG, AWb);
  k_small64<<<64, 256, 0, stream>>>(M, A, AG, MA, AGA);
  k_cnew<<<1024, 256, 0, stream>>>(A, sumresp, cen, bmap, Wm, cnew);
  k_bias<<<2048, 256, 0, stream>>>(pwB, out);
  k_sA<<<dim3(SA_GRIDX, 2), 256, 0, stream>>>(che, chb, nch, cnt, tokidx, tokr,
                                              tslot, y, cnew, out);
  k_finalize<<<1, 256, 0, stream>>>(gsum, M, A, AG, CC0, RR, MA, AGA, Xsum, Wb,
                                    bb, sumresp, cb, AWb, out);
}

// Round 9
// 402.260 us; speedup vs baseline: 1.1434x; 1.0910x over previous
//
#include <hip/hip_runtime.h>
#include <hip/hip_bf16.h>

// Problem dims
constexpr int N_TOK = 2048;   // T*B
constexpr int C_    = 256;    // in features (== R == OUT)
constexpr int NE    = 64;     // experts
constexpr int D_    = 65536;  // R*OUT centroid dim
constexpr float DECAYF = 0.999f;
constexpr float OMD    = 0.001f;
constexpr float ALPHA  = OMD / 2048.0f;   // (1-decay)/N
constexpr float RTHRESH = 1e-5f;
constexpr int CHMAX = 8448;
constexpr int SA_GRIDX = 512;

using bf16x8 = __attribute__((ext_vector_type(8))) short;
using f32x4  = __attribute__((ext_vector_type(4))) float;
using u16 = unsigned short;

// ---------- workspace layout (float offsets) ----------
constexpr size_t OFF_S     = 0;        // 65536  (spare)
constexpr size_t OFF_XSUM  = 65536;    // 256
constexpr size_t OFF_G     = 65792;    // 65536  G = W^T W (full)
constexpr size_t OFF_M     = 131328;   // 16384  M = cen @ W
constexpr size_t OFF_WB    = 147712;   // 256    Wb = b^T W
constexpr size_t OFF_BB    = 147968;   // 16     bb[0] = ||b||^2 ; bb[1] = gsum
constexpr size_t OFF_SUMR  = 147984;   // 64     sum_n resp
constexpr size_t OFF_A     = 148048;   // 16384  A = resp^T X
constexpr size_t OFF_CC0   = 164432;   // 4096   cen cen^T
constexpr size_t OFF_RR    = 168528;   // 4096   resp^T resp
constexpr size_t OFF_CNT   = 172624;   // 64     per-expert token counts (uint)
constexpr size_t OFF_CN2   = 172688;   // 64     (unused; cn2 == diag(CC0))
constexpr size_t OFF_CB    = 172752;   // 64
constexpr size_t OFF_TSLOT = 172816;   // 2048   per-token writer count (int)
constexpr size_t ZFLOATS   = 174864;
// overwritten-before-read zone:
constexpr size_t OFF_RESP  = 174864;   // 131072
constexpr size_t OFF_AG    = 174864;   // 16384 (overlay after resp dead)
constexpr size_t OFF_MA    = 191248;   // 4096
constexpr size_t OFF_AGA   = 195344;   // 4096
constexpr size_t OFF_AWB   = 199440;   // 64
constexpr size_t OFF_CHE   = 199504;   // 8448
constexpr size_t OFF_CHB   = 207952;   // 8448
constexpr size_t OFF_NCH   = 216400;   // 16
constexpr size_t OFF_Y     = 305936;   // 524288 y = X @ pw^T
constexpr size_t OFF_CNEW  = 830224;   // 4194304 ; also k_M partials (256*16384, exact fit)
constexpr size_t OFF_TIDX  = 5024528;  // 131072 (int)
constexpr size_t OFF_TOKR  = 5155600;  // 131072
// ---- bf16 + scratch extension. SIZE AUDIT (R2/R4 overlap lesson):
//   bf16[256][65536] = 16,777,216 u16 = 8,388,608 floats
constexpr size_t OFF_WTH   = 5286672;               // + 8,388,608 -> 13,675,280
constexpr size_t OFF_SCG   = 13675280;              // k_G3 partials, 2,621,440
constexpr size_t OFF_SCC   = 16296720;              // k_CCp partials, 2,097,152
constexpr size_t WS_FAST2_END = 18393872;           // 73.6 MB (R6 fill counter: ws = 256 MiB)

__device__ __forceinline__ unsigned pack_bf2(float a, float b) {
  __hip_bfloat16 ha = __float2bfloat16(a), hb = __float2bfloat16(b);
  unsigned short ua = *reinterpret_cast<unsigned short*>(&ha);
  unsigned short ub = *reinterpret_cast<unsigned short*>(&hb);
  return (unsigned)ua | ((unsigned)ub << 16);
}

// ======== k_pre: fused bb (4) + Xsum (32) + Wb (256) = grid 292 ========
__global__ __launch_bounds__(256) void k_pre(const float* __restrict__ bmap,
    const float* __restrict__ x, const float* __restrict__ W,
    float* __restrict__ bb, float* __restrict__ xsum, float* __restrict__ Wb) {
  int bx = blockIdx.x;
  int t = threadIdx.x;
  if (bx < 4) {
    // ---- bb[0] = ||b||^2 ----
    int base = bx * 16384 + t;
    float s = 0.f;
    for (int q = 0; q < 64; q++) { float v = bmap[base + q * 256]; s = fmaf(v, v, s); }
    __shared__ float red[256];
    red[t] = s;
    __syncthreads();
    for (int k = 128; k > 0; k >>= 1) {
      if (t < k) red[t] += red[t + k];
      __syncthreads();
    }
    if (t == 0) atomicAdd(&bb[0], red[0]);
  } else if (bx < 36) {
    // ---- Xsum ----
    int n0 = (bx - 4) * 64;
    float s = 0.f;
    for (int n = 0; n < 64; n++) s += x[(n0 + n) * C_ + t];
    atomicAdd(&xsum[t], s);
  } else {
    // ---- Wb[c] = sum_d b[d] W[d,c] (skip all-zero b chunks) ----
    int d0 = (bx - 36) * 256;
    __shared__ float bs[256];
    __shared__ int any;
    if (t == 0) any = 0;
    __syncthreads();
    float bv = bmap[d0 + t];
    bs[t] = bv;
    if (bv != 0.f) any = 1;
    __syncthreads();
    if (any == 0) return;
    float s = 0.f;
    for (int d = 0; d < 256; d++) s = fmaf(bs[d], W[(size_t)(d0 + d) * C_ + t], s);
    atomicAdd(&Wb[t], s);
  }
}

// ======== generic 64x64 gram-style tile (AR) ========
template<int KCHUNK>
__device__ __forceinline__ void gemm_tt_tile(
    const float* __restrict__ Aop, int lda, int ca,
    const float* __restrict__ Bop, int ldb, int cb,
    int d0, float* __restrict__ Out, int ldo, int ro, int co) {
  __shared__ float Wa[32][68], Wb[32][68];
  int t = threadIdx.x;
  int tx = t & 15, ty = t >> 4;
  int lr = t >> 3, lc = (t & 7) * 8;
  float acc[4][4] = {};
  for (int dk = 0; dk < KCHUNK; dk += 32) {
    const float* Arow = &Aop[(size_t)(d0 + dk + lr) * lda + ca];
    const float* Brow = &Bop[(size_t)(d0 + dk + lr) * ldb + cb];
    float4 a0 = *(const float4*)&Arow[lc];
    float4 a1 = *(const float4*)&Arow[lc + 4];
    float4 b0 = *(const float4*)&Brow[lc];
    float4 b1 = *(const float4*)&Brow[lc + 4];
    __syncthreads();
    *(float4*)&Wa[lr][lc]     = a0;
    *(float4*)&Wa[lr][lc + 4] = a1;
    *(float4*)&Wb[lr][lc]     = b0;
    *(float4*)&Wb[lr][lc + 4] = b1;
    __syncthreads();
    #pragma unroll
    for (int k = 0; k < 32; k++) {
      float4 ra4 = *(const float4*)&Wa[k][ty * 4];
      float4 rb4 = *(const float4*)&Wb[k][tx * 4];
      float ra[4] = {ra4.x, ra4.y, ra4.z, ra4.w};
      float rb[4] = {rb4.x, rb4.y, rb4.z, rb4.w};
      #pragma unroll
      for (int i = 0; i < 4; i++)
        #pragma unroll
        for (int j = 0; j < 4; j++)
          acc[i][j] = fmaf(ra[i], rb[j], acc[i][j]);
    }
  }
  #pragma unroll
  for (int i = 0; i < 4; i++)
    #pragma unroll
    for (int j = 0; j < 4; j++)
      atomicAdd(&Out[(size_t)(ro + ty * 4 + i) * ldo + co + tx * 4 + j], acc[i][j]);
}

// ==================== bf16 W-transpose (hi only; R5-proven) ====================
__global__ __launch_bounds__(256) void k_Tw(const float* __restrict__ W,
    u16* __restrict__ wth) {
  __shared__ float Ls[32][257];
  int t = threadIdx.x;
  int d0 = blockIdx.x * 32;
  int r = t >> 3, c8 = (t & 7) * 32;
  #pragma unroll
  for (int q = 0; q < 8; q++) {
    float4 v = *(const float4*)&W[(size_t)(d0 + r) * 256 + c8 + q * 4];
    Ls[r][c8 + q * 4 + 0] = v.x; Ls[r][c8 + q * 4 + 1] = v.y;
    Ls[r][c8 + q * 4 + 2] = v.z; Ls[r][c8 + q * 4 + 3] = v.w;
  }
  __syncthreads();
  int dq = (t & 3) * 8;
  #pragma unroll
  for (int pQ = 0; pQ < 4; pQ++) {
    int c = pQ * 64 + (t >> 2);
    unsigned hw[4];
    #pragma unroll
    for (int q = 0; q < 4; q++)
      hw[q] = pack_bf2(Ls[dq + 2 * q][c], Ls[dq + 2 * q + 1][c]);
    size_t o = (size_t)c * 65536 + d0 + dq;
    *(uint4*)&wth[o] = make_uint4(hw[0], hw[1], hw[2], hw[3]);
  }
}

// ==================== k_G3: G = Wt_hi Wt_hi^T via MFMA (R5/R6-proven) ========
__global__ __launch_bounds__(256) void k_G3(const u16* __restrict__ wth,
    float* __restrict__ part) {
  int kb = blockIdx.x;
  int p = blockIdx.y;
  int ti = 0, rem0 = p;
  while (rem0 >= 4 - ti) { rem0 -= 4 - ti; ti++; }
  int tj = ti + rem0;
  bool two = (ti != tj);
  const u16* srcA = wth + (size_t)(ti * 64) * 65536;
  const u16* srcB = wth + (size_t)(tj * 64) * 65536;
  __shared__ __align__(16) u16 Ta[8 * 68 * 8], Tb[8 * 68 * 8];
  int t = threadIdx.x, l = t & 63, w = t >> 6;
  int m0 = w * 16, lm = l & 15, g = l >> 4;
  int scol = t >> 3, skseg = t & 7;
  f32x4 acc[4] = {};
  for (int cc = 0; cc < 16; cc++) {
    int k0 = kb * 1024 + cc * 64;
    __syncthreads();   // protect previous chunk's frag reads
    {
      uint4 a0 = *(const uint4*)(srcA + (size_t)scol * 65536 + k0 + skseg * 8);
      uint4 a1 = *(const uint4*)(srcA + (size_t)(scol + 32) * 65536 + k0 + skseg * 8);
      *(uint4*)(Ta + (skseg * 68 + scol) * 8) = a0;
      *(uint4*)(Ta + (skseg * 68 + scol + 32) * 8) = a1;
      if (two) {
        uint4 b0 = *(const uint4*)(srcB + (size_t)scol * 65536 + k0 + skseg * 8);
        uint4 b1 = *(const uint4*)(srcB + (size_t)(scol + 32) * 65536 + k0 + skseg * 8);
        *(uint4*)(Tb + (skseg * 68 + scol) * 8) = b0;
        *(uint4*)(Tb + (skseg * 68 + scol + 32) * 8) = b1;
      }
    }
    __syncthreads();
    const u16* TBp = two ? Tb : Ta;
    #pragma unroll
    for (int ks = 0; ks < 2; ks++) {
      int kq = ks * 4 + g;
      bf16x8 av = *(const bf16x8*)(Ta + (kq * 68 + m0 + lm) * 8);
      #pragma unroll
      for (int j = 0; j < 4; j++) {
        bf16x8 bv = *(const bf16x8*)(TBp + (kq * 68 + j * 16 + lm) * 8);
        acc[j] = __builtin_amdgcn_mfma_f32_16x16x32_bf16(av, bv, acc[j], 0, 0, 0);
      }
    }
  }
  // C/D layout: col = lane&15, row = (lane>>4)*4 + reg  [m89-verified]
  float* pp = &part[((size_t)p * 64 + kb) * 4096];
  #pragma unroll
  for (int j = 0; j < 4; j++)
    #pragma unroll
    for (int r = 0; r < 4; r++)
      pp[(m0 + (l >> 4) * 4 + r) * 64 + j * 16 + lm] = acc[j][r];
}

// ---- fallback G (R1-proven) --
__global__ __launch_bounds__(256) void k_Gslow(const float* __restrict__ W,
    float* __restrict__ part) {
  int p = blockIdx.y;
  int ti = 0, rem0 = p;
  while (rem0 >= 4 - ti) { rem0 -= 4 - ti; ti++; }
  int tj = ti + rem0;
  int c1 = ti * 64, c2 = tj * 64;
  int d0 = blockIdx.x * 1024;
  __shared__ unsigned short Wat[64][40], Wbt[64][40];
  int t = threadIdx.x;
  int h = t >> 7;
  int rem = t & 127;
  int k2 = rem >> 3;
  int c4b = rem & 7;
  int cbase = h ? c2 : c1;
  unsigned short (*dst)[40] = h ? Wbt : Wat;
  int l = t & 63, w = t >> 6;
  int m0 = w * 16;
  int lm = l & 15, q8 = (l >> 4) * 8;
  f32x4 acc[4] = {};
  for (int dk = 0; dk < 1024; dk += 32) {
    __syncthreads();
    #pragma unroll
    for (int it = 0; it < 2; it++) {
      int c4 = c4b + it * 8;
      const float* rp = &W[(size_t)(d0 + dk + k2 * 2) * C_ + cbase + c4 * 4];
      float4 g0 = *(const float4*)rp;
      float4 g1 = *(const float4*)(rp + C_);
      *(unsigned*)&dst[c4 * 4 + 0][k2 * 2] = pack_bf2(g0.x, g1.x);
      *(unsigned*)&dst[c4 * 4 + 1][k2 * 2] = pack_bf2(g0.y, g1.y);
      *(unsigned*)&dst[c4 * 4 + 2][k2 * 2] = pack_bf2(g0.z, g1.z);
      *(unsigned*)&dst[c4 * 4 + 3][k2 * 2] = pack_bf2(g0.w, g1.w);
    }
    __syncthreads();
    bf16x8 av = *(const bf16x8*)&Wat[m0 + lm][q8];
    #pragma unroll
    for (int j = 0; j < 4; j++) {
      bf16x8 bv = *(const bf16x8*)&Wbt[j * 16 + lm][q8];
      acc[j] = __builtin_amdgcn_mfma_f32_16x16x32_bf16(av, bv, acc[j], 0, 0, 0);
    }
  }
  float* pp = &part[((size_t)p * 64 + blockIdx.x) * 4096];
  #pragma unroll
  for (int j = 0; j < 4; j++)
    #pragma unroll
    for (int r = 0; r < 4; r++)
      pp[(m0 + (l >> 4) * 4 + r) * 64 + j * 16 + lm] = acc[j][r];
}

// ---- separate reduce kernels (fallback path only) ----
__global__ __launch_bounds__(256) void k_Gred(const float* __restrict__ part,
    float* __restrict__ G) {
  int p = blockIdx.y;
  int ti = 0, rem0 = p;
  while (rem0 >= 4 - ti) { rem0 -= 4 - ti; ti++; }
  int tj = ti + rem0;
  int i = blockIdx.x * 256 + threadIdx.x;
  const float* base = part + (size_t)p * 64 * 4096 + i;
  float s = 0.f;
  for (int kb = 0; kb < 64; kb++) s += base[(size_t)kb * 4096];
  int r = i >> 6, c = i & 63;
  G[(ti * 64 + r) * C_ + tj * 64 + c] = s;
  if (ti != tj) G[(tj * 64 + c) * C_ + ti * 64 + r] = s;
}

__global__ __launch_bounds__(256) void k_Mred(const float* __restrict__ mpart,
    float* __restrict__ M) {
  int i = blockIdx.x * 256 + threadIdx.x;
  int kb0 = blockIdx.y * 64;
  float s = 0.f;
  #pragma unroll 8
  for (int kb = 0; kb < 64; kb++) s += mpart[(size_t)(kb0 + kb) * 16384 + i];
  atomicAdd(&M[i], s);
}

__global__ __launch_bounds__(256) void k_CCred(const float* __restrict__ part,
    float* __restrict__ CC0) {
  int i = (blockIdx.x & 15) * 256 + threadIdx.x;
  int kb0 = (blockIdx.x >> 4) * 64;
  float s = 0.f;
  #pragma unroll 8
  for (int kb = 0; kb < 64; kb++) s += part[(size_t)(kb0 + kb) * 4096 + i];
  atomicAdd(&CC0[i], s);
}

// ---- combined reduce (fast2 path): Gred(160) + Mred(256) + CCred(128) ----
__global__ __launch_bounds__(256) void k_redAll(const float* __restrict__ gp,
    const float* __restrict__ mp, const float* __restrict__ cp,
    float* __restrict__ G, float* __restrict__ M, float* __restrict__ CC0) {
  int bx = blockIdx.x;
  if (bx < 160) {
    int p = bx / 16, ib = bx % 16;
    int ti = 0, rem0 = p;
    while (rem0 >= 4 - ti) { rem0 -= 4 - ti; ti++; }
    int tj = ti + rem0;
    int i = ib * 256 + threadIdx.x;
    const float* base = gp + (size_t)p * 64 * 4096 + i;
    float s = 0.f;
    for (int kb = 0; kb < 64; kb++) s += base[(size_t)kb * 4096];
    int r = i >> 6, c = i & 63;
    G[(ti * 64 + r) * C_ + tj * 64 + c] = s;
    if (ti != tj) G[(tj * 64 + c) * C_ + ti * 64 + r] = s;
  } else if (bx < 416) {
    int idx = bx - 160;
    int i = (idx & 63) * 256 + threadIdx.x;
    int kb0 = (idx >> 6) * 64;
    float s = 0.f;
    #pragma unroll 8
    for (int kb = 0; kb < 64; kb++) s += mp[(size_t)(kb0 + kb) * 16384 + i];
    atomicAdd(&M[i], s);
  } else {
    int idx = bx - 416;
    int i = (idx & 15) * 256 + threadIdx.x;
    int kb0 = (idx >> 4) * 64;
    float s = 0.f;
    #pragma unroll 8
    for (int kb = 0; kb < 64; kb++) s += cp[(size_t)(kb0 + kb) * 4096 + i];
    atomicAdd(&CC0[i], s);
  }
}

// ==================== shared pipeline ====================

// ---- k_AR: fused A = resp^T X (y=0..3) and RR = resp^T resp (y=4) ----
__global__ __launch_bounds__(256) void k_AR(const float* __restrict__ resp,
    const float* __restrict__ x, float* __restrict__ A, float* __restrict__ RR) {
  if (blockIdx.y < 4)
    gemm_tt_tile<256>(resp, NE, 0, x, C_, blockIdx.y * 64, blockIdx.x * 256,
                      A, C_, 0, blockIdx.y * 64);
  else
    gemm_tt_tile<256>(resp, NE, 0, resp, NE, 0, blockIdx.x * 256, RR, NE, 0, 0);
}

// ---- sumresp ----
__global__ __launch_bounds__(256) void k_sr(const float* __restrict__ resp,
    float* __restrict__ sumresp) {
  int e = threadIdx.x & 63, part = threadIdx.x >> 6;
  int n0 = blockIdx.x * 256 + part * 64;
  float s = 0.f;
  for (int n = n0; n < n0 + 64; n++) s += resp[n * NE + e];
  __shared__ float red[256];
  red[threadIdx.x] = s;
  __syncthreads();
  if (part == 0)
    atomicAdd(&sumresp[e], red[e] + red[64 + e] + red[128 + e] + red[192 + e]);
}

// ---- M = cen @ W fp32 (R3/R5/R6-proven; logits precision-critical). ksplit 256x256 ----
__global__ __launch_bounds__(256) void k_M(const float* __restrict__ cen,
    const float* __restrict__ W, float* __restrict__ mpart) {
  int kb = blockIdx.x;
  int c0 = blockIdx.y * 64;
  int d0 = kb * 256;
  __shared__ float As[32][68];
  __shared__ float Bs[32][68];
  int t = threadIdx.x;
  int tx = t & 15, ty = t >> 4;
  int e = t >> 2, dg = t & 3;
  int lr = t >> 3, lc = (t & 7) * 8;
  float acc[4][4] = {};
  for (int dk = 0; dk < 256; dk += 32) {
    const float* cr = &cen[(size_t)e * D_ + d0 + dk];
    float4 cv0 = *(const float4*)&cr[dg * 4];
    float4 cv1 = *(const float4*)&cr[16 + dg * 4];
    const float* wr = &W[(size_t)(d0 + dk + lr) * C_ + c0];
    float4 w0 = *(const float4*)&wr[lc];
    float4 w1 = *(const float4*)&wr[lc + 4];
    __syncthreads();
    As[dg * 4 + 0][e] = cv0.x; As[dg * 4 + 1][e] = cv0.y;
    As[dg * 4 + 2][e] = cv0.z; As[dg * 4 + 3][e] = cv0.w;
    As[16 + dg * 4 + 0][e] = cv1.x; As[16 + dg * 4 + 1][e] = cv1.y;
    As[16 + dg * 4 + 2][e] = cv1.z; As[16 + dg * 4 + 3][e] = cv1.w;
    *(float4*)&Bs[lr][lc]     = w0;
    *(float4*)&Bs[lr][lc + 4] = w1;
    __syncthreads();
    #pragma unroll 8
    for (int k = 0; k < 32; k++) {
      float4 ra4 = *(const float4*)&As[k][ty * 4];
      float4 rb4 = *(const float4*)&Bs[k][tx * 4];
      float ra[4] = {ra4.x, ra4.y, ra4.z, ra4.w};
      float rb[4] = {rb4.x, rb4.y, rb4.z, rb4.w};
      #pragma unroll
      for (int i = 0; i < 4; i++)
        #pragma unroll
        for (int j = 0; j < 4; j++)
          acc[i][j] = fmaf(ra[i], rb[j], acc[i][j]);
    }
  }
  float* pp = &mpart[(size_t)kb * 16384];
  #pragma unroll
  for (int i = 0; i < 4; i++)
    *(float4*)&pp[(ty * 4 + i) * C_ + c0 + tx * 4] = *(float4*)&acc[i][0];
}

// ---- CC partials + cb: 512 blocks x 128-d chunk ----
__global__ __launch_bounds__(256) void k_CCp(const float* __restrict__ cen,
    const float* __restrict__ bmap, float* __restrict__ part,
    float* __restrict__ cb) {
  int d0 = blockIdx.x * 128;
  __shared__ float cs[32][68];
  __shared__ float red[256];
  int t = threadIdx.x;
  int e = t >> 2, dg = t & 3;
  int tx = t & 15, ty = t >> 4;
  float acc[4][4] = {};
  float cbp = 0.f;
  for (int dk = 0; dk < 128; dk += 32) {
    const float* cr = &cen[(size_t)e * D_ + d0 + dk];
    float4 v0 = *(const float4*)&cr[dg * 4];
    float4 v1 = *(const float4*)&cr[16 + dg * 4];
    const float* br = &bmap[d0 + dk];
    float4 b0 = *(const float4*)&br[dg * 4];
    float4 b1 = *(const float4*)&br[16 + dg * 4];
    cbp += v0.x * b0.x + v0.y * b0.y + v0.z * b0.z + v0.w * b0.w
         + v1.x * b1.x + v1.y * b1.y + v1.z * b1.z + v1.w * b1.w;
    __syncthreads();
    cs[dg * 4 + 0][e] = v0.x; cs[dg * 4 + 1][e] = v0.y;
    cs[dg * 4 + 2][e] = v0.z; cs[dg * 4 + 3][e] = v0.w;
    cs[16 + dg * 4 + 0][e] = v1.x; cs[16 + dg * 4 + 1][e] = v1.y;
    cs[16 + dg * 4 + 2][e] = v1.z; cs[16 + dg * 4 + 3][e] = v1.w;
    __syncthreads();
    #pragma unroll
    for (int k = 0; k < 32; k++) {
      float4 ra4 = *(const float4*)&cs[k][ty * 4];
      float4 rb4 = *(const float4*)&cs[k][tx * 4];
      float ra[4] = {ra4.x, ra4.y, ra4.z, ra4.w};
      float rb[4] = {rb4.x, rb4.y, rb4.z, rb4.w};
      #pragma unroll
      for (int i = 0; i < 4; i++)
        #pragma unroll
        for (int j = 0; j < 4; j++)
          acc[i][j] = fmaf(ra[i], rb[j], acc[i][j]);
    }
  }
  float* pp = &part[(size_t)blockIdx.x * 4096];
  #pragma unroll
  for (int i = 0; i < 4; i++)
    *(float4*)&pp[(ty * 4 + i) * 64 + tx * 4] = *(float4*)&acc[i][0];
  red[t] = cbp;
  __syncthreads();
  if (t < 64)
    atomicAdd(&cb[t], red[t * 4] + red[t * 4 + 1] + red[t * 4 + 2] + red[t * 4 + 3]);
}

// ---- k_ygs: fused y = X @ pw^T (by 0..3) and gsum = sum_n x_n^T G x_n (by 4..7) ----
__global__ __launch_bounds__(256) void k_ygs(const float* __restrict__ x,
    const float* __restrict__ pw, const float* __restrict__ G,
    float* __restrict__ y, float* __restrict__ gsum) {
  int n0 = blockIdx.x * 64;
  bool isg = blockIdx.y >= 4;
  int k0 = (blockIdx.y & 3) * 64;
  const float* B = isg ? G : pw;   // G symmetric -> row-major read ok
  __shared__ float Xs[64][17], Ps[64][17];
  __shared__ float red[256];
  int t = threadIdx.x;
  int tx = t & 15, ty = t >> 4;
  int r = t >> 2, q4 = (t & 3) * 4;
  float acc[4][4] = {};
  for (int j0 = 0; j0 < 256; j0 += 16) {
    float4 va = *(const float4*)&x[(n0 + r) * C_ + j0 + q4];
    float4 vb = *(const float4*)&B[(k0 + r) * C_ + j0 + q4];
    __syncthreads();
    Xs[r][q4] = va.x; Xs[r][q4+1] = va.y; Xs[r][q4+2] = va.z; Xs[r][q4+3] = va.w;
    Ps[r][q4] = vb.x; Ps[r][q4+1] = vb.y; Ps[r][q4+2] = vb.z; Ps[r][q4+3] = vb.w;
    __syncthreads();
    #pragma unroll
    for (int k = 0; k < 16; k++) {
      float ra[4], rb[4];
      #pragma unroll
      for (int i = 0; i < 4; i++) ra[i] = Xs[ty*4 + i][k];
      #pragma unroll
      for (int j = 0; j < 4; j++) rb[j] = Ps[tx*4 + j][k];
      #pragma unroll
      for (int i = 0; i < 4; i++)
        #pragma unroll
        for (int j = 0; j < 4; j++)
          acc[i][j] = fmaf(ra[i], rb[j], acc[i][j]);
    }
  }
  if (!isg) {
    #pragma unroll
    for (int i = 0; i < 4; i++)
      #pragma unroll
      for (int j = 0; j < 4; j++)
        y[(n0 + ty*4 + i) * C_ + k0 + tx*4 + j] = acc[i][j];
  } else {
    float s = 0.f;
    #pragma unroll
    for (int i = 0; i < 4; i++) {
      float4 xv = *(const float4*)&x[(size_t)(n0 + ty*4 + i) * C_ + k0 + tx*4];
      s += acc[i][0]*xv.x + acc[i][1]*xv.y + acc[i][2]*xv.z + acc[i][3]*xv.w;
    }
    red[t] = s;
    __syncthreads();
    for (int k = 128; k > 0; k >>= 1) {
      if (t < k) red[t] += red[t + k];
      __syncthreads();
    }
    if (t == 0) atomicAdd(gsum, red[0]);
  }
}

// ------- resp softmax, 4 tokens/block (wave = one token; M L2-reads 4x lower) --
__global__ __launch_bounds__(256) void k_resp(const float* __restrict__ x,
    const float* __restrict__ u, const float* __restrict__ M,
    const float* __restrict__ CC0, const float* __restrict__ cb,
    float* __restrict__ resp) {
  int t = threadIdx.x;
  int tok = t >> 6, e = t & 63;
  int n = blockIdx.x * 4 + tok;
  __shared__ float xs[4][256];
  *(float4*)&xs[tok][e * 4] = *(const float4*)&x[n * C_ + e * 4];
  __syncthreads();
  const float* Me = M + e * C_;
  const float* xr = xs[tok];
  float s = 0.f;
  #pragma unroll 8
  for (int j = 0; j < 256; j += 4) {
    float4 m4 = *(const float4*)&Me[j];
    s = fmaf(xr[j],   m4.x, s);
    s = fmaf(xr[j+1], m4.y, s);
    s = fmaf(xr[j+2], m4.z, s);
    s = fmaf(xr[j+3], m4.w, s);
  }
  float uu = u[n * NE + e];
  float g = -logf(-logf(uu));
  float logit = 2.0f * (s + cb[e]) - CC0[e * 65] + g;   // TAU == 1
  float m = logit;
  for (int off = 32; off > 0; off >>= 1) m = fmaxf(m, __shfl_xor(m, off));
  float ex = expf(logit - m);
  float sum = ex;
  for (int off = 32; off > 0; off >>= 1) sum += __shfl_xor(sum, off);
  resp[n * NE + e] = ex / sum;
}

// ------- routing (NO cap — r3 lesson) -------
__global__ __launch_bounds__(256) void k_route(const float* __restrict__ resp,
    unsigned int* __restrict__ cnt, int* __restrict__ tokidx,
    float* __restrict__ tokr, int* __restrict__ tslot) {
  int n = blockIdx.x * 256 + threadIdx.x;
  int s = 0;
  #pragma unroll 4
  for (int e = 0; e < NE; e++) {
    float r = resp[n * NE + e];
    if (r > RTHRESH) {
      unsigned pos = atomicAdd(&cnt[e], 1u);
      tokidx[e * 2048 + pos] = n;
      tokr[e * 2048 + pos] = r;
      s++;
    }
  }
  tslot[n] = s;
}

// ------- planner (parallel fill; R6-proven) -------
__global__ __launch_bounds__(256) void k_plan(const unsigned int* __restrict__ cnt,
    int* __restrict__ che, int* __restrict__ chb, int* __restrict__ nch) {
  __shared__ int cbase[65];
  __shared__ int ncs[64];
  int t = threadIdx.x;
  if (t < 64) ncs[t] = ((int)cnt[t] + 15) >> 4;
  __syncthreads();
  if (t == 0) {
    int s = 0;
    for (int e = 0; e < 64; e++) { cbase[e] = s; s += ncs[e]; }
    cbase[64] = s;
    nch[0] = s < CHMAX ? s : CHMAX;
  }
  __syncthreads();
  for (int e = 0; e < 64; e++) {
    int b0 = cbase[e], nc = cbase[e + 1] - b0;
    for (int i = t; i < nc; i += 256) {
      int idx = b0 + i;
      if (idx < CHMAX) { che[idx] = e; chb[idx] = i * 16; }
    }
  }
}

// ---------------- AG = A @ G, AWb ----------------
__global__ __launch_bounds__(256) void k_ag(const float* __restrict__ A,
    const float* __restrict__ G, const float* __restrict__ Wb,
    float* __restrict__ AG, float* __restrict__ AWb) {
  int e = blockIdx.x, c = threadIdx.x;
  float s = 0.f;
  for (int cp = 0; cp < C_; cp++) s = fmaf(A[e * C_ + cp], G[cp * C_ + c], s);
  AG[e * C_ + c] = s;
  float p = A[e * C_ + c] * Wb[c];
  __shared__ float red[256];
  red[c] = p;
  __syncthreads();
  for (int k = 128; k > 0; k >>= 1) {
    if (c < k) red[c] += red[c + k];
    __syncthreads();
  }
  if (c == 0) AWb[e] = red[0];
}

// ---------------- MA = M A^T, AGA = AG A^T ----------------
__global__ __launch_bounds__(256) void k_small64(const float* __restrict__ M,
    const float* __restrict__ A, const float* __restrict__ AG,
    float* __restrict__ MA, float* __restrict__ AGA) {
  int e = blockIdx.x;
  int f = threadIdx.x >> 2, q = threadIdx.x & 3;
  float s1 = 0.f, s2 = 0.f;
  for (int c = q * 64; c < q * 64 + 64; c++) {
    float a = A[f * C_ + c];
    s1 = fmaf(M[e * C_ + c], a, s1);
    s2 = fmaf(AG[e * C_ + c], a, s2);
  }
  __shared__ float r1[256], r2[256];
  r1[threadIdx.x] = s1; r2[threadIdx.x] = s2;
  __syncthreads();
  if (q == 0) {
    MA[e * NE + f]  = r1[f*4] + r1[f*4+1] + r1[f*4+2] + r1[f*4+3];
    AGA[e * NE + f] = r2[f*4] + r2[f*4+1] + r2[f*4+2] + r2[f*4+3];
  }
}

// ------- cnew[e,d] = decay*cen + alpha*(A_e.W_d + sr_e*b_d)  [MFMA, R6-proven]
__global__ __launch_bounds__(256) void k_cnew(const float* __restrict__ A,
    const float* __restrict__ sumresp, const float* __restrict__ cen,
    const float* __restrict__ bmap, const float* __restrict__ W,
    float* __restrict__ cnew) {
  int d0 = blockIdx.x * 64;
  __shared__ __align__(16) u16 Abf[64 * 264];
  __shared__ __align__(16) u16 Wt[64 * 264];
  __shared__ float srs[64];
  int t = threadIdx.x, l = t & 63;
  int m0 = (t >> 6) * 16, lm = l & 15, g = l >> 4;
  {
    int e = t >> 2, c0 = (t & 3) * 64;
    const float* ar = &A[e * C_ + c0];
    u16* dst = &Abf[e * 264 + c0];
    #pragma unroll
    for (int q = 0; q < 8; q++) {
      float4 v0 = *(const float4*)&ar[q * 8];
      float4 v1 = *(const float4*)&ar[q * 8 + 4];
      *(uint4*)&dst[q * 8] = make_uint4(pack_bf2(v0.x, v0.y), pack_bf2(v0.z, v0.w),
                                        pack_bf2(v1.x, v1.y), pack_bf2(v1.z, v1.w));
    }
    int r = t >> 2;
    const float* wr = &W[(size_t)(d0 + r) * C_ + c0];
    u16* wdst = &Wt[r * 264 + c0];
    #pragma unroll
    for (int q = 0; q < 8; q++) {
      float4 v0 = *(const float4*)&wr[q * 8];
      float4 v1 = *(const float4*)&wr[q * 8 + 4];
      *(uint4*)&wdst[q * 8] = make_uint4(pack_bf2(v0.x, v0.y), pack_bf2(v0.z, v0.w),
                                         pack_bf2(v1.x, v1.y), pack_bf2(v1.z, v1.w));
    }
    if (t < 64) srs[t] = sumresp[t];
  }
  __syncthreads();
  f32x4 acc[4] = {};
  #pragma unroll
  for (int kk = 0; kk < 8; kk++) {
    bf16x8 av = *(const bf16x8*)&Abf[(m0 + lm) * 264 + kk * 32 + g * 8];
    #pragma unroll
    for (int j = 0; j < 4; j++) {
      bf16x8 bv = *(const bf16x8*)&Wt[(j * 16 + lm) * 264 + kk * 32 + g * 8];
      acc[j] = __builtin_amdgcn_mfma_f32_16x16x32_bf16(av, bv, acc[j], 0, 0, 0);
    }
  }
  #pragma unroll
  for (int j = 0; j < 4; j++) {
    int d = d0 + j * 16 + lm;
    float bv = bmap[d];
    #pragma unroll
    for (int r = 0; r < 4; r++) {
      int e = m0 + g * 4 + r;
      size_t o = (size_t)e * D_ + d;
      cnew[o] = DECAYF * cen[o] + ALPHA * (acc[j][r] + srs[e] * bv);
    }
  }
}

// ---------------- out init with bias ----------------
__global__ __launch_bounds__(256) void k_bias(const float* __restrict__ pwB, float* __restrict__ out) {
  int idx = blockIdx.x * 256 + threadIdx.x;
  out[idx] = pwB[idx & 255];
}

// ------- stage A: dense grouped GEMM -------
__global__ __launch_bounds__(256) void k_sA(const int* __restrict__ che,
    const int* __restrict__ chb, const int* __restrict__ nch,
    const unsigned int* __restrict__ cnt, const int* __restrict__ tokidx,
    const float* __restrict__ tokr, const int* __restrict__ tslot,
    const float* __restrict__ y, const float* __restrict__ cnew,
    float* __restrict__ out) {
  int nchv = nch[0];
  int i0 = blockIdx.y * 128;
  __shared__ int nsh[16]; __shared__ float rsh[16]; __shared__ int wsh[16];
  __shared__ float Ys[16][260];
  __shared__ float Bs[32][132];
  int t = threadIdx.x;
  for (int ch = blockIdx.x; ch < nchv; ch += SA_GRIDX) {
    int e = che[ch], base = chb[ch];
    int c = (int)cnt[e];
    __syncthreads();
    if (t < 16) {
      int idx = base + t;
      if (idx < c) {
        int n = tokidx[e * 2048 + idx];
        nsh[t] = n; rsh[t] = tokr[e * 2048 + idx]; wsh[t] = tslot[n];
      } else { nsh[t] = 0; rsh[t] = 0.f; wsh[t] = 2; }
    }
    __syncthreads();
    {
      int row = t >> 4, c0 = (t & 15) * 16;
      const float* yr = &y[nsh[row] * C_ + c0];
      float4 v0 = *(const float4*)&yr[0];
      float4 v1 = *(const float4*)&yr[4];
      float4 v2 = *(const float4*)&yr[8];
      float4 v3 = *(const float4*)&yr[12];
      *(float4*)&Ys[row][c0]      = v0;
      *(float4*)&Ys[row][c0 + 4]  = v1;
      *(float4*)&Ys[row][c0 + 8]  = v2;
      *(float4*)&Ys[row][c0 + 12] = v3;
    }
    int tx = t & 31, ty = t >> 5;
    int br = t >> 1, bk = (t & 1) * 16;
    float acc[2][4] = {};
    for (int k0 = 0; k0 < 256; k0 += 32) {
      const float* Brow = &cnew[(size_t)e * D_ + (size_t)(i0 + br) * C_ + k0 + bk];
      float4 b0 = *(const float4*)&Brow[0];
      float4 b1 = *(const float4*)&Brow[4];
      float4 b2 = *(const float4*)&Brow[8];
      float4 b3 = *(const float4*)&Brow[12];
      __syncthreads();
      Bs[bk+0][br]  = b0.x; Bs[bk+1][br]  = b0.y; Bs[bk+2][br]  = b0.z; Bs[bk+3][br]  = b0.w;
      Bs[bk+4][br]  = b1.x; Bs[bk+5][br]  = b1.y; Bs[bk+6][br]  = b1.z; Bs[bk+7][br]  = b1.w;
      Bs[bk+8][br]  = b2.x; Bs[bk+9][br]  = b2.y; Bs[bk+10][br] = b2.z; Bs[bk+11][br] = b2.w;
      Bs[bk+12][br] = b3.x; Bs[bk+13][br] = b3.y; Bs[bk+14][br] = b3.z; Bs[bk+15][br] = b3.w;
      __syncthreads();
      #pragma unroll
      for (int kk = 0; kk < 32; kk++) {
        float a0 = Ys[ty*2 + 0][k0 + kk];
        float a1 = Ys[ty*2 + 1][k0 + kk];
        float4 bv = *(const float4*)&Bs[kk][tx*4];
        acc[0][0] = fmaf(a0, bv.x, acc[0][0]); acc[0][1] = fmaf(a0, bv.y, acc[0][1]);
        acc[0][2] = fmaf(a0, bv.z, acc[0][2]); acc[0][3] = fmaf(a0, bv.w, acc[0][3]);
        acc[1][0] = fmaf(a1, bv.x, acc[1][0]); acc[1][1] = fmaf(a1, bv.y, acc[1][1]);
        acc[1][2] = fmaf(a1, bv.z, acc[1][2]); acc[1][3] = fmaf(a1, bv.w, acc[1][3]);
      }
    }
    #pragma unroll
    for (int i = 0; i < 2; i++) {
      int tk = ty*2 + i;
      float r = rsh[tk];
      if (r == 0.f) continue;
      int n = nsh[tk];
      float* op = &out[n * C_ + i0 + tx*4];
      if (wsh[tk] == 1) {
        float4 cur = *(const float4*)op;
        cur.x += r * acc[i][0]; cur.y += r * acc[i][1];
        cur.z += r * acc[i][2]; cur.w += r * acc[i][3];
        *(float4*)op = cur;
      } else {
        atomicAdd(op + 0, r * acc[i][0]);
        atomicAdd(op + 1, r * acc[i][1]);
        atomicAdd(op + 2, r * acc[i][2]);
        atomicAdd(op + 3, r * acc[i][3]);
      }
    }
  }
}

// ---------------- loss assembly ----------------
__global__ __launch_bounds__(256) void k_finalize(
    const float* __restrict__ gsum, const float* __restrict__ M,
    const float* __restrict__ A, const float* __restrict__ AG,
    const float* __restrict__ CC0, const float* __restrict__ RR,
    const float* __restrict__ MA, const float* __restrict__ AGA,
    const float* __restrict__ Xsum, const float* __restrict__ Wb,
    const float* __restrict__ bb, const float* __restrict__ sr,
    const float* __restrict__ cb, const float* __restrict__ AWb,
    float* __restrict__ out) {
  int t = threadIdx.x;
  float a_gs = (t == 0) ? gsum[0] : 0.f;
  float a_am = 0.f, a_aag = 0.f;
  for (int i = t; i < 16384; i += 256) {
    float a = A[i];
    a_am  = fmaf(M[i], a, a_am);
    a_aag = fmaf(AG[i], a, a_aag);
  }
  float a_cc = 0.f, a_ma = 0.f, a_aga = 0.f, a_cbsr = 0.f, a_awbsr = 0.f, a_srsr = 0.f;
  for (int p = t; p < 4096; p += 256) {
    float r = RR[p];
    int e = p >> 6, f = p & 63;
    float srf = sr[f];
    a_cc    = fmaf(r, CC0[p], a_cc);
    a_ma    = fmaf(r, MA[p], a_ma);
    a_aga   = fmaf(r, AGA[p], a_aga);
    a_cbsr  = fmaf(r * cb[e], srf, a_cbsr);
    a_awbsr = fmaf(r * AWb[e], srf, a_awbsr);
    a_srsr  = fmaf(r * sr[e], srf, a_srsr);
  }
  float a_xw = Xsum[t] * Wb[t];
  float a_srcb = 0.f, a_srawb = 0.f, a_sr2 = 0.f;
  if (t < 64) { float s = sr[t]; a_srcb = s * cb[t]; a_srawb = s * AWb[t]; a_sr2 = s * s; }
  float v[13] = {a_gs, a_am, a_aag, a_cc, a_ma, a_aga, a_cbsr, a_awbsr, a_srsr,
                 a_xw, a_srcb, a_srawb, a_sr2};
  __shared__ float red[256];
  __shared__ float tot[13];
  for (int q = 0; q < 13; q++) {
    red[t] = v[q];
    __syncthreads();
    for (int s2 = 128; s2 > 0; s2 >>= 1) {
      if (t < s2) red[t] += red[t + s2];
      __syncthreads();
    }
    if (t == 0) tot[q] = red[0];
    __syncthreads();
  }
  if (t == 0) {
    const float q = DECAYF, al = ALPHA;
    float bbv = bb[0];
    float sumkeyf2 = tot[0] + 2.f * tot[9] + 2048.f * bbv;
    float cross = q * (tot[1] + tot[10]) + al * (tot[2] + 2.f * tot[11] + bbv * tot[12]);
    float sumq2 = q*q * tot[3] + 2.f*q*al * (tot[4] + tot[6])
                + al*al * (tot[5] + 2.f * tot[7] + bbv * tot[8]);
    out[524288] = (0.25f / (2048.0f * 65536.0f)) * (sumkeyf2 - 2.f * cross + sumq2);
  }
}

extern "C" void kernel_launch(void* const* d_in, const int* in_sizes, int n_in,
                              void* d_out, int out_size, void* d_ws, size_t ws_size,
                              hipStream_t stream) {
  const float* x    = (const float*)d_in[0];
  const float* u    = (const float*)d_in[1];
  const float* Wm   = (const float*)d_in[2];
  const float* bmap = (const float*)d_in[3];
  const float* pw   = (const float*)d_in[4];
  const float* pwB  = (const float*)d_in[5];
  const float* cen  = (const float*)d_in[6];
  float* out = (float*)d_out;
  float* ws  = (float*)d_ws;

  float* Xsum    = ws + OFF_XSUM;
  float* G       = ws + OFF_G;
  float* M       = ws + OFF_M;
  float* Wb      = ws + OFF_WB;
  float* bb      = ws + OFF_BB;
  float* gsum    = ws + OFF_BB + 1;
  float* sumresp = ws + OFF_SUMR;
  float* A       = ws + OFF_A;
  float* CC0     = ws + OFF_CC0;
  float* RR      = ws + OFF_RR;
  unsigned int* cnt = (unsigned int*)(ws + OFF_CNT);
  float* cb      = ws + OFF_CB;
  int*   tslot   = (int*)(ws + OFF_TSLOT);
  float* resp    = ws + OFF_RESP;
  float* AG      = ws + OFF_AG;
  float* MA      = ws + OFF_MA;
  float* AGA     = ws + OFF_AGA;
  float* AWb     = ws + OFF_AWB;
  int*   che     = (int*)(ws + OFF_CHE);
  int*   chb     = (int*)(ws + OFF_CHB);
  int*   nch     = (int*)(ws + OFF_NCH);
  float* y       = ws + OFF_Y;
  float* cnew    = ws + OFF_CNEW;
  float* scratch = ws + OFF_CNEW;     // fallback sequential-reuse scratch; fast2 M partials
  int*   tokidx  = (int*)(ws + OFF_TIDX);
  float* tokr    = ws + OFF_TOKR;
  u16*   wth     = (u16*)(ws + OFF_WTH);
  float* sc_g    = ws + OFF_SCG;
  float* sc_cc   = ws + OFF_SCC;

  bool fast2 = ws_size >= (size_t)WS_FAST2_END * sizeof(float);

  hipMemsetAsync(d_ws, 0, ZFLOATS * sizeof(float), stream);

  k_pre<<<292, 256, 0, stream>>>(bmap, x, Wm, bb, Xsum, Wb);
  if (fast2) {
    k_Tw<<<2048, 256, 0, stream>>>(Wm, wth);
    k_G3<<<dim3(64, 10), 256, 0, stream>>>(wth, sc_g);
    k_M<<<dim3(256, 4), 256, 0, stream>>>(cen, Wm, scratch);
    k_CCp<<<512, 256, 0, stream>>>(cen, bmap, sc_cc, cb);
    k_redAll<<<544, 256, 0, stream>>>(sc_g, scratch, sc_cc, G, M, CC0);
  } else {
    k_Gslow<<<dim3(64, 10), 256, 0, stream>>>(Wm, scratch);
    k_Gred<<<dim3(16, 10), 256, 0, stream>>>(scratch, G);
    k_M<<<dim3(256, 4), 256, 0, stream>>>(cen, Wm, scratch);
    k_Mred<<<dim3(64, 4), 256, 0, stream>>>(scratch, M);
    k_CCp<<<512, 256, 0, stream>>>(cen, bmap, scratch, cb);
    k_CCred<<<128, 256, 0, stream>>>(scratch, CC0);
  }
  k_ygs<<<dim3(32, 8), 256, 0, stream>>>(x, pw, G, y, gsum);
  k_resp<<<512, 256, 0, stream>>>(x, u, M, CC0, cb, resp);
  k_route<<<8, 256, 0, stream>>>(resp, cnt, tokidx, tokr, tslot);
  k_AR<<<dim3(8, 5), 256, 0, stream>>>(resp, x, A, RR);
  k_sr<<<8, 256, 0, stream>>>(resp, sumresp);
  k_plan<<<1, 256, 0, stream>>>(cnt, che, chb, nch);
  k_ag<<<64, 256, 0, stream>>>(A, G, Wb, AG, AWb);
  k_small64<<<64, 256, 0, stream>>>(M, A, AG, MA, AGA);
  k_cnew<<<1024, 256, 0, stream>>>(A, sumresp, cen, bmap, Wm, cnew);
  k_bias<<<2048, 256, 0, stream>>>(pwB, out);
  k_sA<<<dim3(SA_GRIDX, 2), 256, 0, stream>>>(che, chb, nch, cnt, tokidx, tokr,
                                              tslot, y, cnew, out);
  k_finalize<<<1, 256, 0, stream>>>(gsum, M, A, AG, CC0, RR, MA, AGA, Xsum, Wb,
                                    bb, sumresp, cb, AWb, out);
}

// Round 10
// 331.840 us; speedup vs baseline: 1.3860x; 1.2122x over previous
//
#include <hip/hip_runtime.h>
#include <hip/hip_bf16.h>

// Problem dims
constexpr int N_TOK = 2048;   // T*B
constexpr int C_    = 256;    // in features (== R == OUT)
constexpr int NE    = 64;     // experts
constexpr int D_    = 65536;  // R*OUT centroid dim
constexpr float DECAYF = 0.999f;
constexpr float OMD    = 0.001f;
constexpr float ALPHA  = OMD / 2048.0f;   // (1-decay)/N
constexpr float RTHRESH = 1e-5f;
constexpr int CHMAX = 8448;

using bf16x8 = __attribute__((ext_vector_type(8))) short;
using f32x4  = __attribute__((ext_vector_type(4))) float;
using u16 = unsigned short;

// ---------- workspace layout (float offsets) ----------
constexpr size_t OFF_XSUM  = 65536;    // 256
constexpr size_t OFF_G     = 65792;    // 65536  G = W^T W (full)
constexpr size_t OFF_M     = 131328;   // 16384  M = cen @ W
constexpr size_t OFF_WB    = 147712;   // 256    Wb = b^T W
constexpr size_t OFF_BB    = 147968;   // 16     bb[0] = ||b||^2 ; bb[1] = gsum
constexpr size_t OFF_SUMR  = 147984;   // 64     sum_n resp
constexpr size_t OFF_A     = 148048;   // 16384  A = resp^T X
constexpr size_t OFF_CC0   = 164432;   // 4096   cen cen^T
constexpr size_t OFF_RR    = 168528;   // 4096   resp^T resp
constexpr size_t OFF_CNT   = 172624;   // 64     per-expert token counts (uint)
constexpr size_t OFF_CB    = 172752;   // 64
constexpr size_t OFF_TSLOT = 172816;   // 2048   per-token writer count (int)
constexpr size_t ZFLOATS   = 174864;
// overwritten-before-read zone:
constexpr size_t OFF_RESP  = 174864;   // 131072
constexpr size_t OFF_AG    = 174864;   // 16384 (overlay after resp dead)
constexpr size_t OFF_MA    = 191248;   // 4096
constexpr size_t OFF_AGA   = 195344;   // 4096
constexpr size_t OFF_AWB   = 199440;   // 64
constexpr size_t OFF_CHE   = 199504;   // 8448
constexpr size_t OFF_CHB   = 207952;   // 8448
constexpr size_t OFF_NCH   = 216400;   // 16
constexpr size_t OFF_Y     = 305936;   // 524288 y = X @ pw^T
constexpr size_t OFF_CNEW  = 830224;   // 4194304 ; also k_M partials (256*16384, exact fit)
constexpr size_t OFF_TIDX  = 5024528;  // 131072 (int)
constexpr size_t OFF_TOKR  = 5155600;  // 131072
// ---- bf16 + scratch extension. SIZE AUDIT (R2/R4 overlap lesson):
//   bf16[256][65536] = 16,777,216 u16 = 8,388,608 floats
constexpr size_t OFF_WTH   = 5286672;               // + 8,388,608 -> 13,675,280
constexpr size_t OFF_SCG   = 13675280;              // k_G3 partials, 2,621,440
constexpr size_t OFF_SCC   = 16296720;              // k_CCp partials, 2,097,152
constexpr size_t WS_FAST2_END = 18393872;           // 73.6 MB (R6 fill counter: ws = 256 MiB)

__device__ __forceinline__ unsigned pack_bf2(float a, float b) {
  __hip_bfloat16 ha = __float2bfloat16(a), hb = __float2bfloat16(b);
  unsigned short ua = *reinterpret_cast<unsigned short*>(&ha);
  unsigned short ub = *reinterpret_cast<unsigned short*>(&hb);
  return (unsigned)ua | ((unsigned)ub << 16);
}

// ================= k_preTw: pre (292) + Tw (2048) = 2340 blocks =================
__global__ __launch_bounds__(256) void k_preTw(const float* __restrict__ bmap,
    const float* __restrict__ x, const float* __restrict__ W,
    float* __restrict__ bb, float* __restrict__ xsum, float* __restrict__ Wb,
    u16* __restrict__ wth) {
  __shared__ __align__(16) char smem[32896];
  int bx = blockIdx.x;
  int t = threadIdx.x;
  if (bx < 4) {
    float* red = (float*)smem;
    int base = bx * 16384 + t;
    float s = 0.f;
    for (int q = 0; q < 64; q++) { float v = bmap[base + q * 256]; s = fmaf(v, v, s); }
    red[t] = s;
    __syncthreads();
    for (int k = 128; k > 0; k >>= 1) {
      if (t < k) red[t] += red[t + k];
      __syncthreads();
    }
    if (t == 0) atomicAdd(&bb[0], red[0]);
  } else if (bx < 36) {
    int n0 = (bx - 4) * 64;
    float s = 0.f;
    for (int n = 0; n < 64; n++) s += x[(n0 + n) * C_ + t];
    atomicAdd(&xsum[t], s);
  } else if (bx < 292) {
    float* bs = (float*)smem;
    __shared__ int any;
    int d0 = (bx - 36) * 256;
    if (t == 0) any = 0;
    __syncthreads();
    float bv = bmap[d0 + t];
    bs[t] = bv;
    if (bv != 0.f) any = 1;
    __syncthreads();
    if (any == 0) return;
    float s = 0.f;
    for (int d = 0; d < 256; d++) s = fmaf(bs[d], W[(size_t)(d0 + d) * C_ + t], s);
    atomicAdd(&Wb[t], s);
  } else {
    // ---- Tw: W -> wth bf16 [256][65536] transposed ----
    float (*Ls)[257] = (float(*)[257])smem;
    int d0 = (bx - 292) * 32;
    int r = t >> 3, c8 = (t & 7) * 32;
    #pragma unroll
    for (int q = 0; q < 8; q++) {
      float4 v = *(const float4*)&W[(size_t)(d0 + r) * 256 + c8 + q * 4];
      Ls[r][c8 + q * 4 + 0] = v.x; Ls[r][c8 + q * 4 + 1] = v.y;
      Ls[r][c8 + q * 4 + 2] = v.z; Ls[r][c8 + q * 4 + 3] = v.w;
    }
    __syncthreads();
    int dq = (t & 3) * 8;
    #pragma unroll
    for (int pQ = 0; pQ < 4; pQ++) {
      int c = pQ * 64 + (t >> 2);
      unsigned hw[4];
      #pragma unroll
      for (int q = 0; q < 4; q++)
        hw[q] = pack_bf2(Ls[dq + 2 * q][c], Ls[dq + 2 * q + 1][c]);
      size_t o = (size_t)c * 65536 + d0 + dq;
      *(uint4*)&wth[o] = make_uint4(hw[0], hw[1], hw[2], hw[3]);
    }
  }
}

// ========== k_big1: G3 (640) + M (1024) + CCp (512) = 2176 blocks ==========
__global__ __launch_bounds__(256) void k_big1(const u16* __restrict__ wth,
    const float* __restrict__ cen, const float* __restrict__ W,
    const float* __restrict__ bmap, float* __restrict__ gpart,
    float* __restrict__ mpart, float* __restrict__ cpart, float* __restrict__ cb) {
  __shared__ __align__(16) char smem[17408];
  int bx = blockIdx.x;
  int t = threadIdx.x;
  if (bx < 640) {
    // ---- G3 ----
    u16* Ta = (u16*)smem;             // 4352 u16
    u16* Tb = Ta + 4352;
    int kb = bx & 63, p = bx >> 6;
    int ti = 0, rem0 = p;
    while (rem0 >= 4 - ti) { rem0 -= 4 - ti; ti++; }
    int tj = ti + rem0;
    bool two = (ti != tj);
    const u16* srcA = wth + (size_t)(ti * 64) * 65536;
    const u16* srcB = wth + (size_t)(tj * 64) * 65536;
    int l = t & 63, w = t >> 6;
    int m0 = w * 16, lm = l & 15, g = l >> 4;
    int scol = t >> 3, skseg = t & 7;
    f32x4 acc[4] = {};
    for (int cc = 0; cc < 16; cc++) {
      int k0 = kb * 1024 + cc * 64;
      __syncthreads();
      {
        uint4 a0 = *(const uint4*)(srcA + (size_t)scol * 65536 + k0 + skseg * 8);
        uint4 a1 = *(const uint4*)(srcA + (size_t)(scol + 32) * 65536 + k0 + skseg * 8);
        *(uint4*)(Ta + (skseg * 68 + scol) * 8) = a0;
        *(uint4*)(Ta + (skseg * 68 + scol + 32) * 8) = a1;
        if (two) {
          uint4 b0 = *(const uint4*)(srcB + (size_t)scol * 65536 + k0 + skseg * 8);
          uint4 b1 = *(const uint4*)(srcB + (size_t)(scol + 32) * 65536 + k0 + skseg * 8);
          *(uint4*)(Tb + (skseg * 68 + scol) * 8) = b0;
          *(uint4*)(Tb + (skseg * 68 + scol + 32) * 8) = b1;
        }
      }
      __syncthreads();
      const u16* TBp = two ? Tb : Ta;
      #pragma unroll
      for (int ks = 0; ks < 2; ks++) {
        int kq = ks * 4 + g;
        bf16x8 av = *(const bf16x8*)(Ta + (kq * 68 + m0 + lm) * 8);
        #pragma unroll
        for (int j = 0; j < 4; j++) {
          bf16x8 bv = *(const bf16x8*)(TBp + (kq * 68 + j * 16 + lm) * 8);
          acc[j] = __builtin_amdgcn_mfma_f32_16x16x32_bf16(av, bv, acc[j], 0, 0, 0);
        }
      }
    }
    float* pp = &gpart[((size_t)p * 64 + kb) * 4096];
    #pragma unroll
    for (int j = 0; j < 4; j++)
      #pragma unroll
      for (int r = 0; r < 4; r++)
        pp[(m0 + (l >> 4) * 4 + r) * 64 + j * 16 + lm] = acc[j][r];
  } else if (bx < 1664) {
    // ---- M (fp32, precision-critical) ----
    float (*As)[68] = (float(*)[68])smem;
    float (*Bs)[68] = (float(*)[68])(smem + 8704);
    int idx = bx - 640;
    int kb = idx & 255, c0 = (idx >> 8) * 64;
    int d0 = kb * 256;
    int tx = t & 15, ty = t >> 4;
    int e = t >> 2, dg = t & 3;
    int lr = t >> 3, lc = (t & 7) * 8;
    float acc[4][4] = {};
    for (int dk = 0; dk < 256; dk += 32) {
      const float* cr = &cen[(size_t)e * D_ + d0 + dk];
      float4 cv0 = *(const float4*)&cr[dg * 4];
      float4 cv1 = *(const float4*)&cr[16 + dg * 4];
      const float* wr = &W[(size_t)(d0 + dk + lr) * C_ + c0];
      float4 w0 = *(const float4*)&wr[lc];
      float4 w1 = *(const float4*)&wr[lc + 4];
      __syncthreads();
      As[dg * 4 + 0][e] = cv0.x; As[dg * 4 + 1][e] = cv0.y;
      As[dg * 4 + 2][e] = cv0.z; As[dg * 4 + 3][e] = cv0.w;
      As[16 + dg * 4 + 0][e] = cv1.x; As[16 + dg * 4 + 1][e] = cv1.y;
      As[16 + dg * 4 + 2][e] = cv1.z; As[16 + dg * 4 + 3][e] = cv1.w;
      *(float4*)&Bs[lr][lc]     = w0;
      *(float4*)&Bs[lr][lc + 4] = w1;
      __syncthreads();
      #pragma unroll 8
      for (int k = 0; k < 32; k++) {
        float4 ra4 = *(const float4*)&As[k][ty * 4];
        float4 rb4 = *(const float4*)&Bs[k][tx * 4];
        float ra[4] = {ra4.x, ra4.y, ra4.z, ra4.w};
        float rb[4] = {rb4.x, rb4.y, rb4.z, rb4.w};
        #pragma unroll
        for (int i = 0; i < 4; i++)
          #pragma unroll
          for (int j = 0; j < 4; j++)
            acc[i][j] = fmaf(ra[i], rb[j], acc[i][j]);
      }
    }
    float* pp = &mpart[(size_t)kb * 16384];
    #pragma unroll
    for (int i = 0; i < 4; i++)
      *(float4*)&pp[(ty * 4 + i) * C_ + c0 + tx * 4] = *(float4*)&acc[i][0];
  } else {
    // ---- CCp + cb ----
    float (*cs)[68] = (float(*)[68])smem;
    float* red = (float*)(smem + 8704);
    int d0 = (bx - 1664) * 128;
    int e = t >> 2, dg = t & 3;
    int tx = t & 15, ty = t >> 4;
    float acc[4][4] = {};
    float cbp = 0.f;
    for (int dk = 0; dk < 128; dk += 32) {
      const float* cr = &cen[(size_t)e * D_ + d0 + dk];
      float4 v0 = *(const float4*)&cr[dg * 4];
      float4 v1 = *(const float4*)&cr[16 + dg * 4];
      const float* br = &bmap[d0 + dk];
      float4 b0 = *(const float4*)&br[dg * 4];
      float4 b1 = *(const float4*)&br[16 + dg * 4];
      cbp += v0.x * b0.x + v0.y * b0.y + v0.z * b0.z + v0.w * b0.w
           + v1.x * b1.x + v1.y * b1.y + v1.z * b1.z + v1.w * b1.w;
      __syncthreads();
      cs[dg * 4 + 0][e] = v0.x; cs[dg * 4 + 1][e] = v0.y;
      cs[dg * 4 + 2][e] = v0.z; cs[dg * 4 + 3][e] = v0.w;
      cs[16 + dg * 4 + 0][e] = v1.x; cs[16 + dg * 4 + 1][e] = v1.y;
      cs[16 + dg * 4 + 2][e] = v1.z; cs[16 + dg * 4 + 3][e] = v1.w;
      __syncthreads();
      #pragma unroll
      for (int k = 0; k < 32; k++) {
        float4 ra4 = *(const float4*)&cs[k][ty * 4];
        float4 rb4 = *(const float4*)&cs[k][tx * 4];
        float ra[4] = {ra4.x, ra4.y, ra4.z, ra4.w};
        float rb[4] = {rb4.x, rb4.y, rb4.z, rb4.w};
        #pragma unroll
        for (int i = 0; i < 4; i++)
          #pragma unroll
          for (int j = 0; j < 4; j++)
            acc[i][j] = fmaf(ra[i], rb[j], acc[i][j]);
      }
    }
    float* pp = &cpart[(size_t)(bx - 1664) * 4096];
    #pragma unroll
    for (int i = 0; i < 4; i++)
      *(float4*)&pp[(ty * 4 + i) * 64 + tx * 4] = *(float4*)&acc[i][0];
    red[t] = cbp;
    __syncthreads();
    if (t < 64)
      atomicAdd(&cb[t], red[t * 4] + red[t * 4 + 1] + red[t * 4 + 2] + red[t * 4 + 3]);
  }
}

// ---- combined reduce: Gred(160) + Mred(256) + CCred(128) = 544 ----
__global__ __launch_bounds__(256) void k_redAll(const float* __restrict__ gp,
    const float* __restrict__ mp, const float* __restrict__ cp,
    float* __restrict__ G, float* __restrict__ M, float* __restrict__ CC0) {
  int bx = blockIdx.x;
  if (bx < 160) {
    int p = bx / 16, ib = bx % 16;
    int ti = 0, rem0 = p;
    while (rem0 >= 4 - ti) { rem0 -= 4 - ti; ti++; }
    int tj = ti + rem0;
    int i = ib * 256 + threadIdx.x;
    const float* base = gp + (size_t)p * 64 * 4096 + i;
    float s = 0.f;
    for (int kb = 0; kb < 64; kb++) s += base[(size_t)kb * 4096];
    int r = i >> 6, c = i & 63;
    G[(ti * 64 + r) * C_ + tj * 64 + c] = s;
    if (ti != tj) G[(tj * 64 + c) * C_ + ti * 64 + r] = s;
  } else if (bx < 416) {
    int idx = bx - 160;
    int i = (idx & 63) * 256 + threadIdx.x;
    int kb0 = (idx >> 6) * 64;
    float s = 0.f;
    #pragma unroll 8
    for (int kb = 0; kb < 64; kb++) s += mp[(size_t)(kb0 + kb) * 16384 + i];
    atomicAdd(&M[i], s);
  } else {
    int idx = bx - 416;
    int i = (idx & 15) * 256 + threadIdx.x;
    int kb0 = (idx >> 4) * 64;
    float s = 0.f;
    #pragma unroll 8
    for (int kb = 0; kb < 64; kb++) s += cp[(size_t)(kb0 + kb) * 4096 + i];
    atomicAdd(&CC0[i], s);
  }
}

// ===== k_big2: ygs (256) + resp/route/sr wave-fused (512) = 768 blocks =====
__global__ __launch_bounds__(256) void k_big2(const float* __restrict__ x,
    const float* __restrict__ pw, const float* __restrict__ G,
    const float* __restrict__ u, const float* __restrict__ M,
    const float* __restrict__ CC0, const float* __restrict__ cb,
    float* __restrict__ y, float* __restrict__ gsum, float* __restrict__ resp,
    unsigned int* __restrict__ cnt, int* __restrict__ tokidx,
    float* __restrict__ tokr, int* __restrict__ tslot,
    float* __restrict__ sumresp) {
  __shared__ __align__(16) char smem[9728];
  int bx = blockIdx.x;
  int t = threadIdx.x;
  if (bx < 256) {
    // ---- ygs ----
    float (*Xs)[17] = (float(*)[17])smem;
    float (*Ps)[17] = (float(*)[17])(smem + 4352);
    float* red = (float*)(smem + 8704);
    int n0 = (bx & 31) * 64;
    int by = bx >> 5;
    bool isg = by >= 4;
    int k0 = (by & 3) * 64;
    const float* B = isg ? G : pw;
    int tx = t & 15, ty = t >> 4;
    int r = t >> 2, q4 = (t & 3) * 4;
    float acc[4][4] = {};
    for (int j0 = 0; j0 < 256; j0 += 16) {
      float4 va = *(const float4*)&x[(n0 + r) * C_ + j0 + q4];
      float4 vb = *(const float4*)&B[(k0 + r) * C_ + j0 + q4];
      __syncthreads();
      Xs[r][q4] = va.x; Xs[r][q4+1] = va.y; Xs[r][q4+2] = va.z; Xs[r][q4+3] = va.w;
      Ps[r][q4] = vb.x; Ps[r][q4+1] = vb.y; Ps[r][q4+2] = vb.z; Ps[r][q4+3] = vb.w;
      __syncthreads();
      #pragma unroll
      for (int k = 0; k < 16; k++) {
        float ra[4], rb[4];
        #pragma unroll
        for (int i = 0; i < 4; i++) ra[i] = Xs[ty*4 + i][k];
        #pragma unroll
        for (int j = 0; j < 4; j++) rb[j] = Ps[tx*4 + j][k];
        #pragma unroll
        for (int i = 0; i < 4; i++)
          #pragma unroll
          for (int j = 0; j < 4; j++)
            acc[i][j] = fmaf(ra[i], rb[j], acc[i][j]);
      }
    }
    if (!isg) {
      #pragma unroll
      for (int i = 0; i < 4; i++)
        #pragma unroll
        for (int j = 0; j < 4; j++)
          y[(n0 + ty*4 + i) * C_ + k0 + tx*4 + j] = acc[i][j];
    } else {
      float s = 0.f;
      #pragma unroll
      for (int i = 0; i < 4; i++) {
        float4 xv = *(const float4*)&x[(size_t)(n0 + ty*4 + i) * C_ + k0 + tx*4];
        s += acc[i][0]*xv.x + acc[i][1]*xv.y + acc[i][2]*xv.z + acc[i][3]*xv.w;
      }
      red[t] = s;
      __syncthreads();
      for (int k = 128; k > 0; k >>= 1) {
        if (t < k) red[t] += red[t + k];
        __syncthreads();
      }
      if (t == 0) atomicAdd(gsum, red[0]);
    }
  } else {
    // ---- resp softmax + route + sr (wave = one token) ----
    float* xs   = (float*)smem;          // [4][256]
    float* ssum = xs + 1024;             // [64]
    int tok = t >> 6, e = t & 63;
    int n = (bx - 256) * 4 + tok;
    if (t < 64) ssum[t] = 0.f;
    *(float4*)&xs[tok * 256 + e * 4] = *(const float4*)&x[n * C_ + e * 4];
    __syncthreads();
    const float* Me = M + e * C_;
    const float* xr = &xs[tok * 256];
    float s = 0.f;
    #pragma unroll 8
    for (int j = 0; j < 256; j += 4) {
      float4 m4 = *(const float4*)&Me[j];
      s = fmaf(xr[j],   m4.x, s);
      s = fmaf(xr[j+1], m4.y, s);
      s = fmaf(xr[j+2], m4.z, s);
      s = fmaf(xr[j+3], m4.w, s);
    }
    float uu = u[n * NE + e];
    float g = -logf(-logf(uu));
    float logit = 2.0f * (s + cb[e]) - CC0[e * 65] + g;   // TAU == 1
    float m = logit;
    for (int off = 32; off > 0; off >>= 1) m = fmaxf(m, __shfl_xor(m, off));
    float ex = expf(logit - m);
    float sum = ex;
    for (int off = 32; off > 0; off >>= 1) sum += __shfl_xor(sum, off);
    float r = ex / sum;
    resp[n * NE + e] = r;
    // route (ballot over the wave = this token's 64 experts)
    bool take = r > RTHRESH;
    unsigned long long mask = __ballot(take);
    if (take) {
      unsigned pos = atomicAdd(&cnt[e], 1u);
      tokidx[e * 2048 + pos] = n;
      tokr[e * 2048 + pos] = r;
    }
    if (e == 0) tslot[n] = (int)__popcll(mask);
    // sr: block-level accumulate then one atomic per e
    atomicAdd(&ssum[e], r);
    __syncthreads();
    if (t < 64) atomicAdd(&sumresp[t], ssum[t]);
  }
}

// ===== k_big3: AR (40) + plan (1) = 41 blocks =====
__global__ __launch_bounds__(256) void k_big3(const float* __restrict__ resp,
    const float* __restrict__ x, float* __restrict__ A, float* __restrict__ RR,
    const unsigned int* __restrict__ cnt, int* __restrict__ che,
    int* __restrict__ chb, int* __restrict__ nch) {
  __shared__ __align__(16) char smem[17408];
  int bx = blockIdx.x;
  int t = threadIdx.x;
  if (bx < 40) {
    // ---- gram tile: A (y 0..3) / RR (y 4) ----
    int by = bx >> 3, bxx = bx & 7;
    const float* Aop = resp; int lda = NE, ca = 0;
    const float* Bop; int ldb, cbn; float* Out; int ldo, co;
    if (by < 4) { Bop = x; ldb = C_; cbn = by * 64; Out = A; ldo = C_; co = by * 64; }
    else        { Bop = resp; ldb = NE; cbn = 0; Out = RR; ldo = NE; co = 0; }
    int d0 = bxx * 256;
    float (*Wa)[68] = (float(*)[68])smem;
    float (*Wb)[68] = (float(*)[68])(smem + 8704);
    int tx = t & 15, ty = t >> 4;
    int lr = t >> 3, lc = (t & 7) * 8;
    float acc[4][4] = {};
    for (int dk = 0; dk < 256; dk += 32) {
      const float* Arow = &Aop[(size_t)(d0 + dk + lr) * lda + ca];
      const float* Brow = &Bop[(size_t)(d0 + dk + lr) * ldb + cbn];
      float4 a0 = *(const float4*)&Arow[lc];
      float4 a1 = *(const float4*)&Arow[lc + 4];
      float4 b0 = *(const float4*)&Brow[lc];
      float4 b1 = *(const float4*)&Brow[lc + 4];
      __syncthreads();
      *(float4*)&Wa[lr][lc]     = a0;
      *(float4*)&Wa[lr][lc + 4] = a1;
      *(float4*)&Wb[lr][lc]     = b0;
      *(float4*)&Wb[lr][lc + 4] = b1;
      __syncthreads();
      #pragma unroll
      for (int k = 0; k < 32; k++) {
        float4 ra4 = *(const float4*)&Wa[k][ty * 4];
        float4 rb4 = *(const float4*)&Wb[k][tx * 4];
        float ra[4] = {ra4.x, ra4.y, ra4.z, ra4.w};
        float rb[4] = {rb4.x, rb4.y, rb4.z, rb4.w};
        #pragma unroll
        for (int i = 0; i < 4; i++)
          #pragma unroll
          for (int j = 0; j < 4; j++)
            acc[i][j] = fmaf(ra[i], rb[j], acc[i][j]);
      }
    }
    #pragma unroll
    for (int i = 0; i < 4; i++)
      #pragma unroll
      for (int j = 0; j < 4; j++)
        atomicAdd(&Out[(size_t)(ty * 4 + i) * ldo + co + tx * 4 + j], acc[i][j]);
  } else {
    // ---- plan ----
    int* cbase = (int*)smem;      // 65
    int* ncs   = cbase + 65;      // 64
    if (t < 64) ncs[t] = ((int)cnt[t] + 15) >> 4;
    __syncthreads();
    if (t == 0) {
      int s = 0;
      for (int e = 0; e < 64; e++) { cbase[e] = s; s += ncs[e]; }
      cbase[64] = s;
      nch[0] = s < CHMAX ? s : CHMAX;
    }
    __syncthreads();
    for (int e = 0; e < 64; e++) {
      int b0 = cbase[e], nc = cbase[e + 1] - b0;
      for (int i = t; i < nc; i += 256) {
        int idx = b0 + i;
        if (idx < CHMAX) { che[idx] = e; chb[idx] = i * 16; }
      }
    }
  }
}

// ===== k_big4: ag (64) + cnew (1024) + bias (2048) = 3136 blocks =====
__global__ __launch_bounds__(256) void k_big4(const float* __restrict__ A,
    const float* __restrict__ G, const float* __restrict__ Wb,
    const float* __restrict__ sumresp, const float* __restrict__ cen,
    const float* __restrict__ bmap, const float* __restrict__ W,
    const float* __restrict__ pwB, float* __restrict__ AG,
    float* __restrict__ AWb, float* __restrict__ cnew, float* __restrict__ out) {
  __shared__ __align__(16) char smem[67840];
  int bx = blockIdx.x;
  int t = threadIdx.x;
  if (bx < 64) {
    // ---- ag ----
    float* red = (float*)smem;
    int e = bx, c = t;
    float s = 0.f;
    for (int cp = 0; cp < C_; cp++) s = fmaf(A[e * C_ + cp], G[cp * C_ + c], s);
    AG[e * C_ + c] = s;
    float p = A[e * C_ + c] * Wb[c];
    red[c] = p;
    __syncthreads();
    for (int k = 128; k > 0; k >>= 1) {
      if (c < k) red[c] += red[c + k];
      __syncthreads();
    }
    if (c == 0) AWb[e] = red[0];
  } else if (bx < 1088) {
    // ---- cnew (MFMA, R6-proven) ----
    u16* Abf = (u16*)smem;                     // 64*264
    u16* Wt  = Abf + 64 * 264;                 // 64*264
    float* srs = (float*)(Wt + 64 * 264);      // 64
    int d0 = (bx - 64) * 64;
    int l = t & 63;
    int m0 = (t >> 6) * 16, lm = l & 15, g = l >> 4;
    {
      int e = t >> 2, c0 = (t & 3) * 64;
      const float* ar = &A[e * C_ + c0];
      u16* dst = &Abf[e * 264 + c0];
      #pragma unroll
      for (int q = 0; q < 8; q++) {
        float4 v0 = *(const float4*)&ar[q * 8];
        float4 v1 = *(const float4*)&ar[q * 8 + 4];
        *(uint4*)&dst[q * 8] = make_uint4(pack_bf2(v0.x, v0.y), pack_bf2(v0.z, v0.w),
                                          pack_bf2(v1.x, v1.y), pack_bf2(v1.z, v1.w));
      }
      int r = t >> 2;
      const float* wr = &W[(size_t)(d0 + r) * C_ + c0];
      u16* wdst = &Wt[r * 264 + c0];
      #pragma unroll
      for (int q = 0; q < 8; q++) {
        float4 v0 = *(const float4*)&wr[q * 8];
        float4 v1 = *(const float4*)&wr[q * 8 + 4];
        *(uint4*)&wdst[q * 8] = make_uint4(pack_bf2(v0.x, v0.y), pack_bf2(v0.z, v0.w),
                                           pack_bf2(v1.x, v1.y), pack_bf2(v1.z, v1.w));
      }
      if (t < 64) srs[t] = sumresp[t];
    }
    __syncthreads();
    f32x4 acc[4] = {};
    #pragma unroll
    for (int kk = 0; kk < 8; kk++) {
      bf16x8 av = *(const bf16x8*)&Abf[(m0 + lm) * 264 + kk * 32 + g * 8];
      #pragma unroll
      for (int j = 0; j < 4; j++) {
        bf16x8 bv = *(const bf16x8*)&Wt[(j * 16 + lm) * 264 + kk * 32 + g * 8];
        acc[j] = __builtin_amdgcn_mfma_f32_16x16x32_bf16(av, bv, acc[j], 0, 0, 0);
      }
    }
    #pragma unroll
    for (int j = 0; j < 4; j++) {
      int d = d0 + j * 16 + lm;
      float bv = bmap[d];
      #pragma unroll
      for (int r = 0; r < 4; r++) {
        int e = m0 + g * 4 + r;
        size_t o = (size_t)e * D_ + d;
        cnew[o] = DECAYF * cen[o] + ALPHA * (acc[j][r] + srs[e] * bv);
      }
    }
  } else {
    // ---- bias ----
    int idx = (bx - 1088) * 256 + t;
    out[idx] = pwB[idx & 255];
  }
}

// ===== k_sAs: sA (1024) + small64 (64) = 1088 blocks =====
__global__ __launch_bounds__(256) void k_sAs(const int* __restrict__ che,
    const int* __restrict__ chb, const int* __restrict__ nch,
    const unsigned int* __restrict__ cnt, const int* __restrict__ tokidx,
    const float* __restrict__ tokr, const int* __restrict__ tslot,
    const float* __restrict__ y, const float* __restrict__ cnew,
    const float* __restrict__ M, const float* __restrict__ A,
    const float* __restrict__ AG, float* __restrict__ MA,
    float* __restrict__ AGA, float* __restrict__ out) {
  __shared__ __align__(16) char smem[33728];
  int bx = blockIdx.x;
  int t = threadIdx.x;
  if (bx < 1024) {
    // ---- sA ----
    int* nsh = (int*)smem;                       // 16
    float* rsh = (float*)(smem + 64);            // 16
    int* wsh = (int*)(smem + 128);               // 16
    float (*Ys)[260] = (float(*)[260])(smem + 192);          // 16x260
    float (*Bs)[132] = (float(*)[132])(smem + 192 + 16640);  // 32x132
    int nchv = nch[0];
    int i0 = (bx >> 9) * 128;
    int chx = bx & 511;
    for (int ch = chx; ch < nchv; ch += 512) {
      int e = che[ch], base = chb[ch];
      int c = (int)cnt[e];
      __syncthreads();
      if (t < 16) {
        int idx = base + t;
        if (idx < c) {
          int n = tokidx[e * 2048 + idx];
          nsh[t] = n; rsh[t] = tokr[e * 2048 + idx]; wsh[t] = tslot[n];
        } else { nsh[t] = 0; rsh[t] = 0.f; wsh[t] = 2; }
      }
      __syncthreads();
      {
        int row = t >> 4, c0 = (t & 15) * 16;
        const float* yr = &y[nsh[row] * C_ + c0];
        float4 v0 = *(const float4*)&yr[0];
        float4 v1 = *(const float4*)&yr[4];
        float4 v2 = *(const float4*)&yr[8];
        float4 v3 = *(const float4*)&yr[12];
        *(float4*)&Ys[row][c0]      = v0;
        *(float4*)&Ys[row][c0 + 4]  = v1;
        *(float4*)&Ys[row][c0 + 8]  = v2;
        *(float4*)&Ys[row][c0 + 12] = v3;
      }
      int tx = t & 31, ty = t >> 5;
      int br = t >> 1, bk = (t & 1) * 16;
      float acc[2][4] = {};
      for (int k0 = 0; k0 < 256; k0 += 32) {
        const float* Brow = &cnew[(size_t)e * D_ + (size_t)(i0 + br) * C_ + k0 + bk];
        float4 b0 = *(const float4*)&Brow[0];
        float4 b1 = *(const float4*)&Brow[4];
        float4 b2 = *(const float4*)&Brow[8];
        float4 b3 = *(const float4*)&Brow[12];
        __syncthreads();
        Bs[bk+0][br]  = b0.x; Bs[bk+1][br]  = b0.y; Bs[bk+2][br]  = b0.z; Bs[bk+3][br]  = b0.w;
        Bs[bk+4][br]  = b1.x; Bs[bk+5][br]  = b1.y; Bs[bk+6][br]  = b1.z; Bs[bk+7][br]  = b1.w;
        Bs[bk+8][br]  = b2.x; Bs[bk+9][br]  = b2.y; Bs[bk+10][br] = b2.z; Bs[bk+11][br] = b2.w;
        Bs[bk+12][br] = b3.x; Bs[bk+13][br] = b3.y; Bs[bk+14][br] = b3.z; Bs[bk+15][br] = b3.w;
        __syncthreads();
        #pragma unroll
        for (int kk = 0; kk < 32; kk++) {
          float a0 = Ys[ty*2 + 0][k0 + kk];
          float a1 = Ys[ty*2 + 1][k0 + kk];
          float4 bv = *(const float4*)&Bs[kk][tx*4];
          acc[0][0] = fmaf(a0, bv.x, acc[0][0]); acc[0][1] = fmaf(a0, bv.y, acc[0][1]);
          acc[0][2] = fmaf(a0, bv.z, acc[0][2]); acc[0][3] = fmaf(a0, bv.w, acc[0][3]);
          acc[1][0] = fmaf(a1, bv.x, acc[1][0]); acc[1][1] = fmaf(a1, bv.y, acc[1][1]);
          acc[1][2] = fmaf(a1, bv.z, acc[1][2]); acc[1][3] = fmaf(a1, bv.w, acc[1][3]);
        }
      }
      #pragma unroll
      for (int i = 0; i < 2; i++) {
        int tk = ty*2 + i;
        float r = rsh[tk];
        if (r == 0.f) continue;
        int n = nsh[tk];
        float* op = &out[n * C_ + i0 + tx*4];
        if (wsh[tk] == 1) {
          float4 cur = *(const float4*)op;
          cur.x += r * acc[i][0]; cur.y += r * acc[i][1];
          cur.z += r * acc[i][2]; cur.w += r * acc[i][3];
          *(float4*)op = cur;
        } else {
          atomicAdd(op + 0, r * acc[i][0]);
          atomicAdd(op + 1, r * acc[i][1]);
          atomicAdd(op + 2, r * acc[i][2]);
          atomicAdd(op + 3, r * acc[i][3]);
        }
      }
    }
  } else {
    // ---- small64: MA = M A^T, AGA = AG A^T ----
    float* r1 = (float*)smem;
    float* r2 = r1 + 256;
    int e = bx - 1024;
    int f = t >> 2, q = t & 3;
    float s1 = 0.f, s2 = 0.f;
    for (int c = q * 64; c < q * 64 + 64; c++) {
      float a = A[f * C_ + c];
      s1 = fmaf(M[e * C_ + c], a, s1);
      s2 = fmaf(AG[e * C_ + c], a, s2);
    }
    r1[t] = s1; r2[t] = s2;
    __syncthreads();
    if (q == 0) {
      MA[e * NE + f]  = r1[f*4] + r1[f*4+1] + r1[f*4+2] + r1[f*4+3];
      AGA[e * NE + f] = r2[f*4] + r2[f*4+1] + r2[f*4+2] + r2[f*4+3];
    }
  }
}

// ---------------- loss assembly ----------------
__global__ __launch_bounds__(256) void k_finalize(
    const float* __restrict__ gsum, const float* __restrict__ M,
    const float* __restrict__ A, const float* __restrict__ AG,
    const float* __restrict__ CC0, const float* __restrict__ RR,
    const float* __restrict__ MA, const float* __restrict__ AGA,
    const float* __restrict__ Xsum, const float* __restrict__ Wb,
    const float* __restrict__ bb, const float* __restrict__ sr,
    const float* __restrict__ cb, const float* __restrict__ AWb,
    float* __restrict__ out) {
  int t = threadIdx.x;
  float a_gs = (t == 0) ? gsum[0] : 0.f;
  float a_am = 0.f, a_aag = 0.f;
  for (int i = t; i < 16384; i += 256) {
    float a = A[i];
    a_am  = fmaf(M[i], a, a_am);
    a_aag = fmaf(AG[i], a, a_aag);
  }
  float a_cc = 0.f, a_ma = 0.f, a_aga = 0.f, a_cbsr = 0.f, a_awbsr = 0.f, a_srsr = 0.f;
  for (int p = t; p < 4096; p += 256) {
    float r = RR[p];
    int e = p >> 6, f = p & 63;
    float srf = sr[f];
    a_cc    = fmaf(r, CC0[p], a_cc);
    a_ma    = fmaf(r, MA[p], a_ma);
    a_aga   = fmaf(r, AGA[p], a_aga);
    a_cbsr  = fmaf(r * cb[e], srf, a_cbsr);
    a_awbsr = fmaf(r * AWb[e], srf, a_awbsr);
    a_srsr  = fmaf(r * sr[e], srf, a_srsr);
  }
  float a_xw = Xsum[t] * Wb[t];
  float a_srcb = 0.f, a_srawb = 0.f, a_sr2 = 0.f;
  if (t < 64) { float s = sr[t]; a_srcb = s * cb[t]; a_srawb = s * AWb[t]; a_sr2 = s * s; }
  float v[13] = {a_gs, a_am, a_aag, a_cc, a_ma, a_aga, a_cbsr, a_awbsr, a_srsr,
                 a_xw, a_srcb, a_srawb, a_sr2};
  __shared__ float red[256];
  __shared__ float tot[13];
  for (int q = 0; q < 13; q++) {
    red[t] = v[q];
    __syncthreads();
    for (int s2 = 128; s2 > 0; s2 >>= 1) {
      if (t < s2) red[t] += red[t + s2];
      __syncthreads();
    }
    if (t == 0) tot[q] = red[0];
    __syncthreads();
  }
  if (t == 0) {
    const float q = DECAYF, al = ALPHA;
    float bbv = bb[0];
    float sumkeyf2 = tot[0] + 2.f * tot[9] + 2048.f * bbv;
    float cross = q * (tot[1] + tot[10]) + al * (tot[2] + 2.f * tot[11] + bbv * tot[12]);
    float sumq2 = q*q * tot[3] + 2.f*q*al * (tot[4] + tot[6])
                + al*al * (tot[5] + 2.f * tot[7] + bbv * tot[8]);
    out[524288] = (0.25f / (2048.0f * 65536.0f)) * (sumkeyf2 - 2.f * cross + sumq2);
  }
}

// ======= fallback-path kernels (unreachable with proven 256MiB ws; kept) =======
__global__ __launch_bounds__(256) void k_Gslow(const float* __restrict__ W,
    float* __restrict__ part) {
  int p = blockIdx.y;
  int ti = 0, rem0 = p;
  while (rem0 >= 4 - ti) { rem0 -= 4 - ti; ti++; }
  int tj = ti + rem0;
  int c1 = ti * 64, c2 = tj * 64;
  int d0 = blockIdx.x * 1024;
  __shared__ unsigned short Wat[64][40], Wbt[64][40];
  int t = threadIdx.x;
  int h = t >> 7;
  int rem = t & 127;
  int k2 = rem >> 3;
  int c4b = rem & 7;
  int cbase = h ? c2 : c1;
  unsigned short (*dst)[40] = h ? Wbt : Wat;
  int l = t & 63, w = t >> 6;
  int m0 = w * 16;
  int lm = l & 15, q8 = (l >> 4) * 8;
  f32x4 acc[4] = {};
  for (int dk = 0; dk < 1024; dk += 32) {
    __syncthreads();
    #pragma unroll
    for (int it = 0; it < 2; it++) {
      int c4 = c4b + it * 8;
      const float* rp = &W[(size_t)(d0 + dk + k2 * 2) * C_ + cbase + c4 * 4];
      float4 g0 = *(const float4*)rp;
      float4 g1 = *(const float4*)(rp + C_);
      *(unsigned*)&dst[c4 * 4 + 0][k2 * 2] = pack_bf2(g0.x, g1.x);
      *(unsigned*)&dst[c4 * 4 + 1][k2 * 2] = pack_bf2(g0.y, g1.y);
      *(unsigned*)&dst[c4 * 4 + 2][k2 * 2] = pack_bf2(g0.z, g1.z);
      *(unsigned*)&dst[c4 * 4 + 3][k2 * 2] = pack_bf2(g0.w, g1.w);
    }
    __syncthreads();
    bf16x8 av = *(const bf16x8*)&Wat[m0 + lm][q8];
    #pragma unroll
    for (int j = 0; j < 4; j++) {
      bf16x8 bv = *(const bf16x8*)&Wbt[j * 16 + lm][q8];
      acc[j] = __builtin_amdgcn_mfma_f32_16x16x32_bf16(av, bv, acc[j], 0, 0, 0);
    }
  }
  float* pp = &part[((size_t)p * 64 + blockIdx.x) * 4096];
  #pragma unroll
  for (int j = 0; j < 4; j++)
    #pragma unroll
    for (int r = 0; r < 4; r++)
      pp[(m0 + (l >> 4) * 4 + r) * 64 + j * 16 + lm] = acc[j][r];
}

extern "C" void kernel_launch(void* const* d_in, const int* in_sizes, int n_in,
                              void* d_out, int out_size, void* d_ws, size_t ws_size,
                              hipStream_t stream) {
  const float* x    = (const float*)d_in[0];
  const float* u    = (const float*)d_in[1];
  const float* Wm   = (const float*)d_in[2];
  const float* bmap = (const float*)d_in[3];
  const float* pw   = (const float*)d_in[4];
  const float* pwB  = (const float*)d_in[5];
  const float* cen  = (const float*)d_in[6];
  float* out = (float*)d_out;
  float* ws  = (float*)d_ws;

  float* Xsum    = ws + OFF_XSUM;
  float* G       = ws + OFF_G;
  float* M       = ws + OFF_M;
  float* Wb      = ws + OFF_WB;
  float* bb      = ws + OFF_BB;
  float* gsum    = ws + OFF_BB + 1;
  float* sumresp = ws + OFF_SUMR;
  float* A       = ws + OFF_A;
  float* CC0     = ws + OFF_CC0;
  float* RR      = ws + OFF_RR;
  unsigned int* cnt = (unsigned int*)(ws + OFF_CNT);
  float* cb      = ws + OFF_CB;
  int*   tslot   = (int*)(ws + OFF_TSLOT);
  float* resp    = ws + OFF_RESP;
  float* AG      = ws + OFF_AG;
  float* MA      = ws + OFF_MA;
  float* AGA     = ws + OFF_AGA;
  float* AWb     = ws + OFF_AWB;
  int*   che     = (int*)(ws + OFF_CHE);
  int*   chb     = (int*)(ws + OFF_CHB);
  int*   nch     = (int*)(ws + OFF_NCH);
  float* y       = ws + OFF_Y;
  float* cnew    = ws + OFF_CNEW;
  float* scratch = ws + OFF_CNEW;     // M partials (pre-cnew)
  int*   tokidx  = (int*)(ws + OFF_TIDX);
  float* tokr    = ws + OFF_TOKR;
  u16*   wth     = (u16*)(ws + OFF_WTH);
  float* sc_g    = ws + OFF_SCG;
  float* sc_cc   = ws + OFF_SCC;

  bool fast2 = ws_size >= (size_t)WS_FAST2_END * sizeof(float);

  hipMemsetAsync(d_ws, 0, ZFLOATS * sizeof(float), stream);

  if (fast2) {
    k_preTw<<<2340, 256, 0, stream>>>(bmap, x, Wm, bb, Xsum, Wb, wth);
    k_big1<<<2176, 256, 0, stream>>>(wth, cen, Wm, bmap, sc_g, scratch, sc_cc, cb);
    k_redAll<<<544, 256, 0, stream>>>(sc_g, scratch, sc_cc, G, M, CC0);
  } else {
    // fallback (never taken with 256MiB ws): unfused G via Gslow into sc region
    k_preTw<<<292, 256, 0, stream>>>(bmap, x, Wm, bb, Xsum, Wb, wth);
    k_Gslow<<<dim3(64, 10), 256, 0, stream>>>(Wm, ws + OFF_CNEW);
    // reuse big1's M+CC branches by launching with G-range skipped is not
    // possible; fallback accepts running big1 fully requires wth -> instead
    // run M+CC via big1 offsets: launch blocks [640,2176) equivalent:
    k_big1<<<2176, 256, 0, stream>>>(wth, cen, Wm, bmap, sc_g, scratch, sc_cc, cb);
    k_redAll<<<544, 256, 0, stream>>>(sc_g, scratch, sc_cc, G, M, CC0);
  }
  k_big2<<<768, 256, 0, stream>>>(x, pw, G, u, M, CC0, cb, y, gsum, resp,
                                  cnt, tokidx, tokr, tslot, sumresp);
  k_big3<<<41, 256, 0, stream>>>(resp, x, A, RR, cnt, che, chb, nch);
  k_big4<<<3136, 256, 0, stream>>>(A, G, Wb, sumresp, cen, bmap, Wm, pwB,
                                   AG, AWb, cnew, out);
  k_sAs<<<1088, 256, 0, stream>>>(che, chb, nch, cnt, tokidx, tokr, tslot,
                                  y, cnew, M, A, AG, MA, AGA, out);
  k_finalize<<<1, 256, 0, stream>>>(gsum, M, A, AG, CC0, RR, MA, AGA, Xsum, Wb,
                                    bb, sumresp, cb, AWb, out);
}